// Round 8
// baseline (875.097 us; speedup 1.0000x reference)
//
#include <hip/hip_runtime.h>
#include <hip/hip_bf16.h>

#define BB 64
#define SS 400
#define HH 512
#define EE 300
#define VV 50000
#define KD 812     // E+H (LSTM input width)
#define KG 1324    // 2H+E (gen_in width)
#define KC 1024    // 2H (out_cat width)
#define BV (BB*VV)

typedef __attribute__((ext_vector_type(8))) short bf16x8;
typedef __attribute__((ext_vector_type(4))) float f32x4;

// ---- workspace layout (float offsets) ----
#define WS_SCORE 0          // [B*S]
#define WS_W     25600      // [B*S]
#define WS_CTX   51200      // [64][512]
#define WS_HNEW  83968      // [64][512]
#define WS_G0    116736     // [2048][64] f32 gate partials x4
#define WS_G1    247808
#define WS_G2    378880
#define WS_G3    509952
#define WS_PGEN  641024     // [64]
#define WS_PART  641088     // [64][8][512] ctx partials
#define WS_ABF   903232     // ushort [64][1024] bf16 out_cat
#define WS_AD1   936000     // ushort [64][832]  bf16 [xe|ctx|0pad]
#define WS_AD2   962624     // ushort [64][512]  bf16 h_prev

__device__ __forceinline__ float sigm(float x){ return 1.f/(1.f+__expf(-x)); }
__device__ __forceinline__ float ftanh(float x){
  x = fminf(fmaxf(x,-15.f),15.f);
  float e = __expf(2.f*x);
  return (e-1.f)/(e+1.f);
}
__device__ __forceinline__ unsigned short f2bf(float f){
  unsigned int u = __builtin_bit_cast(unsigned int, f);
  u += 0x7fffu + ((u>>16)&1u);
  return (unsigned short)(u>>16);
}

// ---- software-pipelined MFMA segment, NAMED ping-pong register sets ----
#define LDW(S, off) { w##S##0 = *(const float4*)(wr + (off)*32); \
                      w##S##1 = *(const float4*)(wr + (off)*32 + 4); }
#define LDA(S, off) { a##S##0 = *(const bf16x8*)(a0 + (off)*32); \
                      a##S##1 = *(const bf16x8*)(a1 + (off)*32); \
                      a##S##2 = *(const bf16x8*)(a2 + (off)*32); \
                      a##S##3 = *(const bf16x8*)(a3 + (off)*32); }
#define CONS(S) { union { bf16x8 v; unsigned int u[4]; } bb_; \
  float4 f0_ = w##S##0; float4 f1_ = w##S##1; \
  asm("v_cvt_pk_bf16_f32 %0, %1, %2" : "=v"(bb_.u[0]) : "v"(f0_.x), "v"(f0_.y)); \
  asm("v_cvt_pk_bf16_f32 %0, %1, %2" : "=v"(bb_.u[1]) : "v"(f0_.z), "v"(f0_.w)); \
  asm("v_cvt_pk_bf16_f32 %0, %1, %2" : "=v"(bb_.u[2]) : "v"(f1_.x), "v"(f1_.y)); \
  asm("v_cvt_pk_bf16_f32 %0, %1, %2" : "=v"(bb_.u[3]) : "v"(f1_.z), "v"(f1_.w)); \
  acc0 = __builtin_amdgcn_mfma_f32_16x16x32_bf16(a##S##0, bb_.v, acc0, 0,0,0); \
  acc1 = __builtin_amdgcn_mfma_f32_16x16x32_bf16(a##S##1, bb_.v, acc1, 0,0,0); \
  acc2 = __builtin_amdgcn_mfma_f32_16x16x32_bf16(a##S##2, bb_.v, acc2, 0,0,0); \
  acc3 = __builtin_amdgcn_mfma_f32_16x16x32_bf16(a##S##3, bb_.v, acc3, 0,0,0); }

// depth-2 pipeline, NSTEP % 2 == 0
template<int NSTEP>
__device__ __forceinline__ void mfma_seg2(const float* __restrict__ wr,
    const unsigned short* __restrict__ a0, const unsigned short* __restrict__ a1,
    const unsigned short* __restrict__ a2, const unsigned short* __restrict__ a3,
    f32x4& acc0, f32x4& acc1, f32x4& acc2, f32x4& acc3)
{
  static_assert(NSTEP % 2 == 0 && NSTEP >= 4, "");
  float4 wA0,wA1, wB0,wB1;
  bf16x8 aA0,aA1,aA2,aA3, aB0,aB1,aB2,aB3;
  LDW(A,0) LDA(A,0)
  LDW(B,1) LDA(B,1)
  #pragma unroll
  for (int ks=0; ks<NSTEP; ks+=2){
    CONS(A) if (ks+2 < NSTEP){ LDW(A,ks+2) LDA(A,ks+2) }
    CONS(B) if (ks+3 < NSTEP){ LDW(B,ks+3) LDA(B,ks+3) }
  }
}

// K0: build bf16 activation buffers: ad1 = [xe(300) | ctx(later) | 0-pad(20)], ad2 = h_prev
__global__ __launch_bounds__(256) void k_prep(const int* __restrict__ x,
    const float* __restrict__ emb, const float* __restrict__ h0,
    unsigned short* __restrict__ ad1, unsigned short* __restrict__ ad2)
{
  int n = blockIdx.x*256 + threadIdx.x;     // 336 blocks: 53248 + 32768
  if (n < BB*832){
    int b = n/832, k = n - b*832;
    if (k < EE) ad1[n] = f2bf(emb[(size_t)x[b]*EE + k]);
    else if (k >= 812) ad1[n] = 0;
  } else {
    int m = n - BB*832;
    ad2[m] = f2bf(h0[m]);
  }
}

// K1: score[b,s] = V_w . tanh(enc[b,s,:] + h_prev[b,:]) + V_b
__global__ __launch_bounds__(256) void k_score(const float* __restrict__ enc,
    const float* __restrict__ h0, const float* __restrict__ Vw,
    const float* __restrict__ Vb, float* __restrict__ score)
{
  int wv = threadIdx.x >> 6, lane = threadIdx.x & 63;
  int pair = blockIdx.x*4 + wv;
  int b = pair / SS;
  int i0 = lane*8;
  const float4* ep = (const float4*)(enc + (size_t)pair*HH + i0);
  const float4* hp = (const float4*)(h0 + b*HH + i0);
  const float4* vp = (const float4*)(Vw + i0);
  float4 e0 = ep[0], e1 = ep[1];
  float4 hv0 = hp[0], hv1 = hp[1];
  float4 v0 = vp[0], v1 = vp[1];
  float sum = ftanh(e0.x+hv0.x)*v0.x + ftanh(e0.y+hv0.y)*v0.y
            + ftanh(e0.z+hv0.z)*v0.z + ftanh(e0.w+hv0.w)*v0.w
            + ftanh(e1.x+hv1.x)*v1.x + ftanh(e1.y+hv1.y)*v1.y
            + ftanh(e1.z+hv1.z)*v1.z + ftanh(e1.w+hv1.w)*v1.w;
  #pragma unroll
  for (int off=32; off; off>>=1) sum += __shfl_xor(sum, off);
  if (lane==0) score[pair] = sum + Vb[0];
}

// K2: per (b, s-chunk): recompute softmax over full row, partial ctx over 50 s.
__global__ __launch_bounds__(256) void k_ctx(const float* __restrict__ enc,
    const float* __restrict__ score, float* __restrict__ wout,
    float* __restrict__ part)
{
  __shared__ float red[256];
  __shared__ float wl[SS];
  int b = blockIdx.x >> 3, sp = blockIdx.x & 7;
  int t = threadIdx.x;
  float v1 = score[b*SS + t];
  float v2 = (t < SS-256) ? score[b*SS + t + 256] : -1e30f;
  red[t] = fmaxf(v1, v2);
  __syncthreads();
  for (int o=128; o; o>>=1){ if (t<o) red[t] = fmaxf(red[t], red[t+o]); __syncthreads(); }
  float mx = red[0];
  __syncthreads();
  float e1 = __expf(v1 - mx);
  float e2 = (t < SS-256) ? __expf(v2 - mx) : 0.f;
  red[t] = e1 + e2;
  __syncthreads();
  for (int o=128; o; o>>=1){ if (t<o) red[t] += red[t+o]; __syncthreads(); }
  float inv = 1.f/red[0];
  float w1 = e1*inv;
  wl[t] = w1;
  if (sp==0) wout[b*SS + t] = w1;
  if (t < SS-256){
    float w2 = e2*inv;
    wl[t+256] = w2;
    if (sp==0) wout[b*SS + t + 256] = w2;
  }
  __syncthreads();
  float a0 = 0.f, a1 = 0.f;
  const float* ebase = enc + ((size_t)b*SS + sp*50)*HH + 2*t;
  #pragma unroll 5
  for (int s=0; s<50; ++s){
    float wg = wl[sp*50 + s];
    float2 e = *(const float2*)(ebase + s*HH);
    a0 += wg * e.x;
    a1 += wg * e.y;
  }
  *(float2*)(part + (size_t)(b*8+sp)*HH + 2*t) = make_float2(a0, a1);
}

// K3: reduce 8 ctx partials -> ctx f32 + ad1 ctx slice (bf16)
__global__ __launch_bounds__(256) void k_ctx_reduce(const float* __restrict__ part,
    float* __restrict__ ctx, unsigned short* __restrict__ ad1)
{
  int b = blockIdx.x, t = threadIdx.x;
  float a0=0.f, a1=0.f;
  #pragma unroll
  for (int sp=0; sp<8; ++sp){
    float2 e = *(const float2*)(part + (size_t)(b*8+sp)*HH + 2*t);
    a0 += e.x; a1 += e.y;
  }
  *(float2*)(ctx + b*HH + 2*t) = make_float2(a0, a1);
  ad1[b*832 + EE + 2*t]     = f2bf(a0);
  ad1[b*832 + EE + 2*t + 1] = f2bf(a1);
}

// K4: gates via MFMA. 512 wave-tiles = 128 j-tiles x 4 K-parts (12/14/8/8 steps).
__global__ __launch_bounds__(128, 4) void k_gates(const float* __restrict__ Wih,
    const float* __restrict__ Whh, const unsigned short* __restrict__ ad1,
    const unsigned short* __restrict__ ad2,
    float* __restrict__ g0, float* __restrict__ g1,
    float* __restrict__ g2, float* __restrict__ g3)
{
  int wt = blockIdx.x*2 + (threadIdx.x >> 6);   // 0..511
  int lane = threadIdx.x & 63;
  int col = lane & 15, kg = lane >> 4;
  int jt = wt >> 2, part = wt & 3;
  int j = jt*16 + col;
  f32x4 acc0={0.f,0.f,0.f,0.f}, acc1=acc0, acc2=acc0, acc3=acc0;
  float* g;
  if (part < 2){
    int k0 = part ? 384 : 0;
    const float* wr = Wih + (size_t)j*KD + k0 + kg*8;
    const unsigned short* a = ad1 + col*832 + k0 + kg*8;
    if (part) mfma_seg2<14>(wr, a, a+16*832, a+32*832, a+48*832, acc0,acc1,acc2,acc3);
    else      mfma_seg2<12>(wr, a, a+16*832, a+32*832, a+48*832, acc0,acc1,acc2,acc3);
    g = part ? g1 : g0;
  } else {
    int k0 = (part==3) ? 256 : 0;
    const float* wr = Whh + (size_t)j*HH + k0 + kg*8;
    const unsigned short* a = ad2 + col*512 + k0 + kg*8;
    mfma_seg2<8>(wr, a, a+16*512, a+32*512, a+48*512, acc0,acc1,acc2,acc3);
    g = (part==3) ? g3 : g2;
  }
  #pragma unroll
  for (int i=0;i<4;i++){
    g[(size_t)j*BB + 0*16 + kg*4 + i] = acc0[i];
    g[(size_t)j*BB + 1*16 + kg*4 + i] = acc1[i];
    g[(size_t)j*BB + 2*16 + kg*4 + i] = acc2[i];
    g[(size_t)j*BB + 3*16 + kg*4 + i] = acc3[i];
  }
}

// K5: LSTM cell elementwise
__global__ __launch_bounds__(256) void k_lstm(const float* __restrict__ c0,
    const float* __restrict__ bih, const float* __restrict__ bhh,
    const float* __restrict__ g0, const float* __restrict__ g1,
    const float* __restrict__ g2, const float* __restrict__ g3,
    const float* __restrict__ ctx, float* __restrict__ hnew,
    unsigned short* __restrict__ abf, float* __restrict__ out)
{
  int n = blockIdx.x*256 + threadIdx.x;   // < 32768
  int b = n & 63, h = n >> 6;
  #define GSUM(off) (g0[(off)*BB+b] + g1[(off)*BB+b] + g2[(off)*BB+b] + g3[(off)*BB+b] + bih[off] + bhh[off])
  float gi = GSUM(h);
  float gf = GSUM(HH+h);
  float gg = GSUM(2*HH+h);
  float go = GSUM(3*HH+h);
  #undef GSUM
  float cn = sigm(gf)*c0[b*HH+h] + sigm(gi)*ftanh(gg);
  float hn = sigm(go)*ftanh(cn);
  out[BV + b*HH + h]          = hn;
  out[BV + BB*HH + b*HH + h]  = cn;
  hnew[b*HH + h] = hn;
  abf[b*KC + h]      = f2bf(hn);
  abf[b*KC + HH + h] = f2bf(ctx[b*HH + h]);
}

// K6: p_gen[b] = sigmoid(gen_w . [ctx, h_new, xe] + gen_b)
__global__ __launch_bounds__(256) void k_pgen(const float* __restrict__ genw,
    const float* __restrict__ genb, const float* __restrict__ ctx,
    const float* __restrict__ hnew, const int* __restrict__ x,
    const float* __restrict__ emb, float* __restrict__ pgen)
{
  __shared__ float red[256];
  int b = blockIdx.x, t = threadIdx.x;
  float p = 0.f;
  for (int k=t; k<KG; k+=256){
    float g = genw[k];
    float v = (k < HH) ? ctx[b*HH + k]
            : (k < 2*HH) ? hnew[b*HH + k - HH]
            : emb[(size_t)x[b]*EE + (k - 2*HH)];
    p += g*v;
  }
  red[t] = p; __syncthreads();
  for (int o=128; o; o>>=1){ if (t<o) red[t] += red[t+o]; __syncthreads(); }
  if (t==0) pgen[b] = sigm(red[0] + genb[0]);
}

// K7 (DIAGNOSTIC x8): out[b,v] = pgen[b]*(out_cat . out_w[v,:] + out_b[v]).
// Identical math repeated 8x (idempotent stores) with memory clobber between
// reps so loads/MFMA can't be CSE'd across reps. Reveals per-dispatch gemm
// time in the rocprof top-5 (8G > fill's 116us). Remove rep loop next round.
__global__ __launch_bounds__(256, 4) void k_gemm(const float* __restrict__ out_w,
    const float* __restrict__ out_b, const unsigned short* __restrict__ abf,
    const float* __restrict__ pgen, float* __restrict__ out)
{
  __shared__ float comb[2][64][17];
  int t = threadIdx.x;
  int wvid = t >> 6, lane = t & 63;
  int vt2 = wvid & 1, kh = wvid >> 1;
  int vt = blockIdx.x*2 + vt2;
  int col = lane & 15, kg = lane >> 4;
  int v = vt*16 + col;
  bool active = (vt < VV/16);
  #pragma unroll 1
  for (int rep=0; rep<8; ++rep){
    f32x4 acc0={0.f,0.f,0.f,0.f}, acc1=acc0, acc2=acc0, acc3=acc0;
    if (active){
      const float* wr = out_w + (size_t)v*KC + kh*512 + kg*8;
      const unsigned short* a = abf + col*KC + kh*512 + kg*8;
      mfma_seg2<16>(wr, a, a+16*KC, a+32*KC, a+48*KC, acc0,acc1,acc2,acc3);
    }
    if (active && kh==1){
      #pragma unroll
      for (int i=0;i<4;i++){
        comb[vt2][0*16 + kg*4 + i][col] = acc0[i];
        comb[vt2][1*16 + kg*4 + i][col] = acc1[i];
        comb[vt2][2*16 + kg*4 + i][col] = acc2[i];
        comb[vt2][3*16 + kg*4 + i][col] = acc3[i];
      }
    }
    __syncthreads();
    if (active && kh==0){
      float ob = out_b[v];
      #pragma unroll
      for (int i=0;i<4;i++){
        int b0 = 0*16 + kg*4 + i;
        int b1 = 1*16 + kg*4 + i;
        int b2 = 2*16 + kg*4 + i;
        int b3 = 3*16 + kg*4 + i;
        out[(size_t)b0*VV + v] = pgen[b0]*(acc0[i] + comb[vt2][b0][col] + ob);
        out[(size_t)b1*VV + v] = pgen[b1]*(acc1[i] + comb[vt2][b1][col] + ob);
        out[(size_t)b2*VV + v] = pgen[b2]*(acc2[i] + comb[vt2][b2][col] + ob);
        out[(size_t)b3*VV + v] = pgen[b3]*(acc3[i] + comb[vt2][b3][col] + ob);
      }
    }
    __syncthreads();
    asm volatile("" ::: "memory");
  }
}

// K8: pointer scatter, last-duplicate-wins; text row staged in LDS, branch-free scan.
__global__ __launch_bounds__(256) void k_scatter(const int* __restrict__ text,
    const float* __restrict__ w, const float* __restrict__ pgen,
    float* __restrict__ out)
{
  __shared__ int ts[SS];
  int b = blockIdx.x, t = threadIdx.x;
  ts[t] = text[b*SS + t];
  if (t + 256 < SS) ts[t+256] = text[b*SS + t + 256];
  __syncthreads();
  float pp = 1.f - pgen[b];
  #pragma unroll
  for (int rep=0; rep<2; ++rep){
    int s = t + rep*256;
    if (s < SS){
      int v = ts[s];
      bool dup = false;
      #pragma unroll 4
      for (int s2=s+1; s2<SS; ++s2) dup = dup || (ts[s2]==v);
      if (!dup) out[(size_t)b*VV + v] += pp * w[b*SS + s];
    }
  }
}

extern "C" void kernel_launch(void* const* d_in, const int* in_sizes, int n_in,
                              void* d_out, int out_size, void* d_ws, size_t ws_size,
                              hipStream_t stream)
{
  const int*   x    = (const int*)  d_in[0];
  const float* enc  = (const float*)d_in[1];
  const float* h0   = (const float*)d_in[2];
  const float* c0   = (const float*)d_in[3];
  const int*   text = (const int*)  d_in[4];
  const float* emb  = (const float*)d_in[6];
  const float* Vw   = (const float*)d_in[7];
  const float* Vb   = (const float*)d_in[8];
  const float* genw = (const float*)d_in[9];
  const float* genb = (const float*)d_in[10];
  const float* outw = (const float*)d_in[11];
  const float* outb = (const float*)d_in[12];
  const float* Wih  = (const float*)d_in[13];
  const float* Whh  = (const float*)d_in[14];
  const float* bih  = (const float*)d_in[15];
  const float* bhh  = (const float*)d_in[16];
  float* out = (float*)d_out;

  float* ws     = (float*)d_ws;
  float* score  = ws + WS_SCORE;
  float* wbuf   = ws + WS_W;
  float* ctx    = ws + WS_CTX;
  float* hnew   = ws + WS_HNEW;
  float* g0     = ws + WS_G0;
  float* g1     = ws + WS_G1;
  float* g2     = ws + WS_G2;
  float* g3     = ws + WS_G3;
  float* pgen   = ws + WS_PGEN;
  float* part   = ws + WS_PART;
  unsigned short* abf = (unsigned short*)(ws + WS_ABF);
  unsigned short* ad1 = (unsigned short*)(ws + WS_AD1);
  unsigned short* ad2 = (unsigned short*)(ws + WS_AD2);

  k_prep<<<336, 256, 0, stream>>>(x, emb, h0, ad1, ad2);
  k_score<<<6400, 256, 0, stream>>>(enc, h0, Vw, Vb, score);
  k_ctx<<<512, 256, 0, stream>>>(enc, score, wbuf, part);
  k_ctx_reduce<<<64, 256, 0, stream>>>(part, ctx, ad1);
  k_gates<<<256, 128, 0, stream>>>(Wih, Whh, ad1, ad2, g0, g1, g2, g3);
  k_lstm<<<128, 256, 0, stream>>>(c0, bih, bhh, g0, g1, g2, g3, ctx, hnew, abf, out);
  k_pgen<<<64, 256, 0, stream>>>(genw, genb, ctx, hnew, x, emb, pgen);
  k_gemm<<<1563, 256, 0, stream>>>(outw, outb, abf, pgen, out);
  k_scatter<<<64, 256, 0, stream>>>(text, wbuf, pgen, out);
}

// Round 9
// 173.356 us; speedup vs baseline: 5.0480x; 5.0480x over previous
//
#include <hip/hip_runtime.h>
#include <hip/hip_bf16.h>

#define BB 64
#define SS 400
#define HH 512
#define EE 300
#define VV 50000
#define KD 812     // E+H (LSTM input width)
#define KG 1324    // 2H+E (gen_in width)
#define KC 1024    // 2H (out_cat width)
#define BV (BB*VV)

typedef __attribute__((ext_vector_type(8))) short bf16x8;
typedef __attribute__((ext_vector_type(4))) float f32x4;

// ---- workspace layout (float offsets) ----
#define WS_SCORE 0          // [B*S]
#define WS_W     25600      // [B*S]
#define WS_CTX   51200      // [64][512]
#define WS_HNEW  83968      // [64][512]
#define WS_G0    116736     // [2048][64] f32 gate partials x4
#define WS_G1    247808
#define WS_G2    378880
#define WS_G3    509952
#define WS_PGEN  641024     // [64]
#define WS_PART  641088     // [64][8][512] ctx partials
#define WS_ABF   903232     // ushort [64][1024] bf16 out_cat
#define WS_AD1   936000     // ushort [64][832]  bf16 [xe|ctx|0pad]
#define WS_AD2   962624     // ushort [64][512]  bf16 h_prev

__device__ __forceinline__ float sigm(float x){ return 1.f/(1.f+__expf(-x)); }
__device__ __forceinline__ float ftanh(float x){
  x = fminf(fmaxf(x,-15.f),15.f);
  float e = __expf(2.f*x);
  return (e-1.f)/(e+1.f);
}
__device__ __forceinline__ unsigned short f2bf(float f){
  unsigned int u = __builtin_bit_cast(unsigned int, f);
  u += 0x7fffu + ((u>>16)&1u);
  return (unsigned short)(u>>16);
}

// ---- software-pipelined MFMA segment (compiler-scheduled; used by k_gates) ----
#define LDW(S, off) { w##S##0 = *(const float4*)(wr + (off)*32); \
                      w##S##1 = *(const float4*)(wr + (off)*32 + 4); }
#define LDA(S, off) { a##S##0 = *(const bf16x8*)(a0 + (off)*32); \
                      a##S##1 = *(const bf16x8*)(a1 + (off)*32); \
                      a##S##2 = *(const bf16x8*)(a2 + (off)*32); \
                      a##S##3 = *(const bf16x8*)(a3 + (off)*32); }
#define CONS(S) { union { bf16x8 v; unsigned int u[4]; } bb_; \
  float4 f0_ = w##S##0; float4 f1_ = w##S##1; \
  asm("v_cvt_pk_bf16_f32 %0, %1, %2" : "=v"(bb_.u[0]) : "v"(f0_.x), "v"(f0_.y)); \
  asm("v_cvt_pk_bf16_f32 %0, %1, %2" : "=v"(bb_.u[1]) : "v"(f0_.z), "v"(f0_.w)); \
  asm("v_cvt_pk_bf16_f32 %0, %1, %2" : "=v"(bb_.u[2]) : "v"(f1_.x), "v"(f1_.y)); \
  asm("v_cvt_pk_bf16_f32 %0, %1, %2" : "=v"(bb_.u[3]) : "v"(f1_.z), "v"(f1_.w)); \
  acc0 = __builtin_amdgcn_mfma_f32_16x16x32_bf16(a##S##0, bb_.v, acc0, 0,0,0); \
  acc1 = __builtin_amdgcn_mfma_f32_16x16x32_bf16(a##S##1, bb_.v, acc1, 0,0,0); \
  acc2 = __builtin_amdgcn_mfma_f32_16x16x32_bf16(a##S##2, bb_.v, acc2, 0,0,0); \
  acc3 = __builtin_amdgcn_mfma_f32_16x16x32_bf16(a##S##3, bb_.v, acc3, 0,0,0); }

// depth-2 pipeline, NSTEP % 2 == 0 (k_gates)
template<int NSTEP>
__device__ __forceinline__ void mfma_seg2(const float* __restrict__ wr,
    const unsigned short* __restrict__ a0, const unsigned short* __restrict__ a1,
    const unsigned short* __restrict__ a2, const unsigned short* __restrict__ a3,
    f32x4& acc0, f32x4& acc1, f32x4& acc2, f32x4& acc3)
{
  static_assert(NSTEP % 2 == 0 && NSTEP >= 4, "");
  float4 wA0,wA1, wB0,wB1;
  bf16x8 aA0,aA1,aA2,aA3, aB0,aB1,aB2,aB3;
  LDW(A,0) LDA(A,0)
  LDW(B,1) LDA(B,1)
  #pragma unroll
  for (int ks=0; ks<NSTEP; ks+=2){
    CONS(A) if (ks+2 < NSTEP){ LDW(A,ks+2) LDA(A,ks+2) }
    CONS(B) if (ks+3 < NSTEP){ LDW(B,ks+3) LDA(B,ks+3) }
  }
}

// ---- T4 machinery for k_gemm: asm loads + counted vmcnt + sched_barrier ----
#define GLD(dst, ptr) \
  asm volatile("global_load_dwordx4 %0, %1, off" : "=v"(dst) : "v"(ptr));
#define GLD16(dst, ptr) \
  asm volatile("global_load_dwordx4 %0, %1, off offset:16" : "=v"(dst) : "v"(ptr));
#define WAITV(N) { asm volatile("s_waitcnt vmcnt(" #N ")"); \
                   __builtin_amdgcn_sched_barrier(0); }
// issue the 6 loads of one K-step into slot S
#define ISSUE(S, step) { \
  const float* wp_ = wr + (step)*32; \
  GLD(w##S##0, wp_) \
  GLD16(w##S##1, wp_) \
  const unsigned short* ap_ = ab + (step)*32; \
  GLD(a##S##0, ap_) \
  GLD(a##S##1, ap_ + 16*KC) \
  GLD(a##S##2, ap_ + 32*KC) \
  GLD(a##S##3, ap_ + 48*KC) }

// K0: build bf16 activation buffers: ad1 = [xe(300) | ctx(later) | 0-pad(20)], ad2 = h_prev
__global__ __launch_bounds__(256) void k_prep(const int* __restrict__ x,
    const float* __restrict__ emb, const float* __restrict__ h0,
    unsigned short* __restrict__ ad1, unsigned short* __restrict__ ad2)
{
  int n = blockIdx.x*256 + threadIdx.x;     // 336 blocks: 53248 + 32768
  if (n < BB*832){
    int b = n/832, k = n - b*832;
    if (k < EE) ad1[n] = f2bf(emb[(size_t)x[b]*EE + k]);
    else if (k >= 812) ad1[n] = 0;
  } else {
    int m = n - BB*832;
    ad2[m] = f2bf(h0[m]);
  }
}

// K1: score[b,s] = V_w . tanh(enc[b,s,:] + h_prev[b,:]) + V_b
__global__ __launch_bounds__(256) void k_score(const float* __restrict__ enc,
    const float* __restrict__ h0, const float* __restrict__ Vw,
    const float* __restrict__ Vb, float* __restrict__ score)
{
  int wv = threadIdx.x >> 6, lane = threadIdx.x & 63;
  int pair = blockIdx.x*4 + wv;
  int b = pair / SS;
  int i0 = lane*8;
  const float4* ep = (const float4*)(enc + (size_t)pair*HH + i0);
  const float4* hp = (const float4*)(h0 + b*HH + i0);
  const float4* vp = (const float4*)(Vw + i0);
  float4 e0 = ep[0], e1 = ep[1];
  float4 hv0 = hp[0], hv1 = hp[1];
  float4 v0 = vp[0], v1 = vp[1];
  float sum = ftanh(e0.x+hv0.x)*v0.x + ftanh(e0.y+hv0.y)*v0.y
            + ftanh(e0.z+hv0.z)*v0.z + ftanh(e0.w+hv0.w)*v0.w
            + ftanh(e1.x+hv1.x)*v1.x + ftanh(e1.y+hv1.y)*v1.y
            + ftanh(e1.z+hv1.z)*v1.z + ftanh(e1.w+hv1.w)*v1.w;
  #pragma unroll
  for (int off=32; off; off>>=1) sum += __shfl_xor(sum, off);
  if (lane==0) score[pair] = sum + Vb[0];
}

// K2: per (b, s-chunk): recompute softmax over full row, partial ctx over 50 s.
__global__ __launch_bounds__(256) void k_ctx(const float* __restrict__ enc,
    const float* __restrict__ score, float* __restrict__ wout,
    float* __restrict__ part)
{
  __shared__ float red[256];
  __shared__ float wl[SS];
  int b = blockIdx.x >> 3, sp = blockIdx.x & 7;
  int t = threadIdx.x;
  float v1 = score[b*SS + t];
  float v2 = (t < SS-256) ? score[b*SS + t + 256] : -1e30f;
  red[t] = fmaxf(v1, v2);
  __syncthreads();
  for (int o=128; o; o>>=1){ if (t<o) red[t] = fmaxf(red[t], red[t+o]); __syncthreads(); }
  float mx = red[0];
  __syncthreads();
  float e1 = __expf(v1 - mx);
  float e2 = (t < SS-256) ? __expf(v2 - mx) : 0.f;
  red[t] = e1 + e2;
  __syncthreads();
  for (int o=128; o; o>>=1){ if (t<o) red[t] += red[t+o]; __syncthreads(); }
  float inv = 1.f/red[0];
  float w1 = e1*inv;
  wl[t] = w1;
  if (sp==0) wout[b*SS + t] = w1;
  if (t < SS-256){
    float w2 = e2*inv;
    wl[t+256] = w2;
    if (sp==0) wout[b*SS + t + 256] = w2;
  }
  __syncthreads();
  float a0 = 0.f, a1 = 0.f;
  const float* ebase = enc + ((size_t)b*SS + sp*50)*HH + 2*t;
  #pragma unroll 5
  for (int s=0; s<50; ++s){
    float wg = wl[sp*50 + s];
    float2 e = *(const float2*)(ebase + s*HH);
    a0 += wg * e.x;
    a1 += wg * e.y;
  }
  *(float2*)(part + (size_t)(b*8+sp)*HH + 2*t) = make_float2(a0, a1);
}

// K3: reduce 8 ctx partials -> ctx f32 + ad1 ctx slice (bf16)
__global__ __launch_bounds__(256) void k_ctx_reduce(const float* __restrict__ part,
    float* __restrict__ ctx, unsigned short* __restrict__ ad1)
{
  int b = blockIdx.x, t = threadIdx.x;
  float a0=0.f, a1=0.f;
  #pragma unroll
  for (int sp=0; sp<8; ++sp){
    float2 e = *(const float2*)(part + (size_t)(b*8+sp)*HH + 2*t);
    a0 += e.x; a1 += e.y;
  }
  *(float2*)(ctx + b*HH + 2*t) = make_float2(a0, a1);
  ad1[b*832 + EE + 2*t]     = f2bf(a0);
  ad1[b*832 + EE + 2*t + 1] = f2bf(a1);
}

// K4: gates via MFMA. 512 wave-tiles = 128 j-tiles x 4 K-parts (12/14/8/8 steps).
__global__ __launch_bounds__(128, 4) void k_gates(const float* __restrict__ Wih,
    const float* __restrict__ Whh, const unsigned short* __restrict__ ad1,
    const unsigned short* __restrict__ ad2,
    float* __restrict__ g0, float* __restrict__ g1,
    float* __restrict__ g2, float* __restrict__ g3)
{
  int wt = blockIdx.x*2 + (threadIdx.x >> 6);   // 0..511
  int lane = threadIdx.x & 63;
  int col = lane & 15, kg = lane >> 4;
  int jt = wt >> 2, part = wt & 3;
  int j = jt*16 + col;
  f32x4 acc0={0.f,0.f,0.f,0.f}, acc1=acc0, acc2=acc0, acc3=acc0;
  float* g;
  if (part < 2){
    int k0 = part ? 384 : 0;
    const float* wr = Wih + (size_t)j*KD + k0 + kg*8;
    const unsigned short* a = ad1 + col*832 + k0 + kg*8;
    if (part) mfma_seg2<14>(wr, a, a+16*832, a+32*832, a+48*832, acc0,acc1,acc2,acc3);
    else      mfma_seg2<12>(wr, a, a+16*832, a+32*832, a+48*832, acc0,acc1,acc2,acc3);
    g = part ? g1 : g0;
  } else {
    int k0 = (part==3) ? 256 : 0;
    const float* wr = Whh + (size_t)j*HH + k0 + kg*8;
    const unsigned short* a = ad2 + col*512 + k0 + kg*8;
    mfma_seg2<8>(wr, a, a+16*512, a+32*512, a+48*512, acc0,acc1,acc2,acc3);
    g = (part==3) ? g3 : g2;
  }
  #pragma unroll
  for (int i=0;i<4;i++){
    g[(size_t)j*BB + 0*16 + kg*4 + i] = acc0[i];
    g[(size_t)j*BB + 1*16 + kg*4 + i] = acc1[i];
    g[(size_t)j*BB + 2*16 + kg*4 + i] = acc2[i];
    g[(size_t)j*BB + 3*16 + kg*4 + i] = acc3[i];
  }
}

// K5: LSTM cell elementwise
__global__ __launch_bounds__(256) void k_lstm(const float* __restrict__ c0,
    const float* __restrict__ bih, const float* __restrict__ bhh,
    const float* __restrict__ g0, const float* __restrict__ g1,
    const float* __restrict__ g2, const float* __restrict__ g3,
    const float* __restrict__ ctx, float* __restrict__ hnew,
    unsigned short* __restrict__ abf, float* __restrict__ out)
{
  int n = blockIdx.x*256 + threadIdx.x;   // < 32768
  int b = n & 63, h = n >> 6;
  #define GSUM(off) (g0[(off)*BB+b] + g1[(off)*BB+b] + g2[(off)*BB+b] + g3[(off)*BB+b] + bih[off] + bhh[off])
  float gi = GSUM(h);
  float gf = GSUM(HH+h);
  float gg = GSUM(2*HH+h);
  float go = GSUM(3*HH+h);
  #undef GSUM
  float cn = sigm(gf)*c0[b*HH+h] + sigm(gi)*ftanh(gg);
  float hn = sigm(go)*ftanh(cn);
  out[BV + b*HH + h]          = hn;
  out[BV + BB*HH + b*HH + h]  = cn;
  hnew[b*HH + h] = hn;
  abf[b*KC + h]      = f2bf(hn);
  abf[b*KC + HH + h] = f2bf(ctx[b*HH + h]);
}

// K6: p_gen[b] = sigmoid(gen_w . [ctx, h_new, xe] + gen_b)
__global__ __launch_bounds__(256) void k_pgen(const float* __restrict__ genw,
    const float* __restrict__ genb, const float* __restrict__ ctx,
    const float* __restrict__ hnew, const int* __restrict__ x,
    const float* __restrict__ emb, float* __restrict__ pgen)
{
  __shared__ float red[256];
  int b = blockIdx.x, t = threadIdx.x;
  float p = 0.f;
  for (int k=t; k<KG; k+=256){
    float g = genw[k];
    float v = (k < HH) ? ctx[b*HH + k]
            : (k < 2*HH) ? hnew[b*HH + k - HH]
            : emb[(size_t)x[b]*EE + (k - 2*HH)];
    p += g*v;
  }
  red[t] = p; __syncthreads();
  for (int o=128; o; o>>=1){ if (t<o) red[t] += red[t+o]; __syncthreads(); }
  if (t==0) pgen[b] = sigm(red[0] + genb[0]);
}

// K7: out[b,v] = pgen[b]*(out_cat . out_w[v,:] + out_b[v]).
// T4: inline-asm global loads + hand-counted s_waitcnt vmcnt(N) + sched_barrier.
// Depth-4 named slots, 6 loads/step, steady wait vmcnt(18) (3 steps in flight),
// tail 18/12/6/0. No LDS, no barriers; waves independent.
__global__ __launch_bounds__(256, 2) void k_gemm(const float* __restrict__ out_w,
    const float* __restrict__ out_b, const unsigned short* __restrict__ abf,
    const float* __restrict__ pgen, float* __restrict__ out)
{
  int wt = blockIdx.x*4 + (threadIdx.x >> 6);   // 782 blocks x4 = 3128 wave-tiles
  if (wt >= VV/16) return;
  int lane = threadIdx.x & 63;
  int col = lane & 15, kg = lane >> 4;
  int v = wt*16 + col;
  const float* wr = out_w + (size_t)v*KC + kg*8;
  const unsigned short* ab = abf + (size_t)col*KC + kg*8;

  float4 wA0,wA1, wB0,wB1, wC0,wC1, wD0,wD1;
  bf16x8 aA0,aA1,aA2,aA3, aB0,aB1,aB2,aB3, aC0,aC1,aC2,aC3, aD0,aD1,aD2,aD3;
  f32x4 acc0={0.f,0.f,0.f,0.f}, acc1=acc0, acc2=acc0, acc3=acc0;

  ISSUE(A,0) ISSUE(B,1) ISSUE(C,2) ISSUE(D,3)
  #pragma unroll
  for (int ks=0; ks<28; ks+=4){
    WAITV(18) CONS(A) ISSUE(A, ks+4)
    WAITV(18) CONS(B) ISSUE(B, ks+5)
    WAITV(18) CONS(C) ISSUE(C, ks+6)
    WAITV(18) CONS(D) ISSUE(D, ks+7)
  }
  WAITV(18) CONS(A)
  WAITV(12) CONS(B)
  WAITV(6)  CONS(C)
  WAITV(0)  CONS(D)

  float ob = out_b[v];
  #pragma unroll
  for (int i=0;i<4;i++){
    int b0 = 0*16 + kg*4 + i;
    int b1 = 1*16 + kg*4 + i;
    int b2 = 2*16 + kg*4 + i;
    int b3 = 3*16 + kg*4 + i;
    out[(size_t)b0*VV + v] = pgen[b0]*(acc0[i] + ob);
    out[(size_t)b1*VV + v] = pgen[b1]*(acc1[i] + ob);
    out[(size_t)b2*VV + v] = pgen[b2]*(acc2[i] + ob);
    out[(size_t)b3*VV + v] = pgen[b3]*(acc3[i] + ob);
  }
}

// K8: pointer scatter, last-duplicate-wins; text row staged in LDS, branch-free scan.
__global__ __launch_bounds__(256) void k_scatter(const int* __restrict__ text,
    const float* __restrict__ w, const float* __restrict__ pgen,
    float* __restrict__ out)
{
  __shared__ int ts[SS];
  int b = blockIdx.x, t = threadIdx.x;
  ts[t] = text[b*SS + t];
  if (t + 256 < SS) ts[t+256] = text[b*SS + t + 256];
  __syncthreads();
  float pp = 1.f - pgen[b];
  #pragma unroll
  for (int rep=0; rep<2; ++rep){
    int s = t + rep*256;
    if (s < SS){
      int v = ts[s];
      bool dup = false;
      #pragma unroll 4
      for (int s2=s+1; s2<SS; ++s2) dup = dup || (ts[s2]==v);
      if (!dup) out[(size_t)b*VV + v] += pp * w[b*SS + s];
    }
  }
}

extern "C" void kernel_launch(void* const* d_in, const int* in_sizes, int n_in,
                              void* d_out, int out_size, void* d_ws, size_t ws_size,
                              hipStream_t stream)
{
  const int*   x    = (const int*)  d_in[0];
  const float* enc  = (const float*)d_in[1];
  const float* h0   = (const float*)d_in[2];
  const float* c0   = (const float*)d_in[3];
  const int*   text = (const int*)  d_in[4];
  const float* emb  = (const float*)d_in[6];
  const float* Vw   = (const float*)d_in[7];
  const float* Vb   = (const float*)d_in[8];
  const float* genw = (const float*)d_in[9];
  const float* genb = (const float*)d_in[10];
  const float* outw = (const float*)d_in[11];
  const float* outb = (const float*)d_in[12];
  const float* Wih  = (const float*)d_in[13];
  const float* Whh  = (const float*)d_in[14];
  const float* bih  = (const float*)d_in[15];
  const float* bhh  = (const float*)d_in[16];
  float* out = (float*)d_out;

  float* ws     = (float*)d_ws;
  float* score  = ws + WS_SCORE;
  float* wbuf   = ws + WS_W;
  float* ctx    = ws + WS_CTX;
  float* hnew   = ws + WS_HNEW;
  float* g0     = ws + WS_G0;
  float* g1     = ws + WS_G1;
  float* g2     = ws + WS_G2;
  float* g3     = ws + WS_G3;
  float* pgen   = ws + WS_PGEN;
  float* part   = ws + WS_PART;
  unsigned short* abf = (unsigned short*)(ws + WS_ABF);
  unsigned short* ad1 = (unsigned short*)(ws + WS_AD1);
  unsigned short* ad2 = (unsigned short*)(ws + WS_AD2);

  k_prep<<<336, 256, 0, stream>>>(x, emb, h0, ad1, ad2);
  k_score<<<6400, 256, 0, stream>>>(enc, h0, Vw, Vb, score);
  k_ctx<<<512, 256, 0, stream>>>(enc, score, wbuf, part);
  k_ctx_reduce<<<64, 256, 0, stream>>>(part, ctx, ad1);
  k_gates<<<256, 128, 0, stream>>>(Wih, Whh, ad1, ad2, g0, g1, g2, g3);
  k_lstm<<<128, 256, 0, stream>>>(c0, bih, bhh, g0, g1, g2, g3, ctx, hnew, abf, out);
  k_pgen<<<64, 256, 0, stream>>>(genw, genb, ctx, hnew, x, emb, pgen);
  k_gemm<<<782, 256, 0, stream>>>(outw, outb, abf, pgen, out);
  k_scatter<<<64, 256, 0, stream>>>(text, wbuf, pgen, out);
}

// Round 10
// 144.197 us; speedup vs baseline: 6.0688x; 1.2022x over previous
//
#include <hip/hip_runtime.h>
#include <hip/hip_bf16.h>

#define BB 64
#define SS 400
#define HH 512
#define EE 300
#define VV 50000
#define KD 812     // E+H (LSTM input width)
#define KG 1324    // 2H+E (gen_in width)
#define KC 1024    // 2H (out_cat width)
#define BV (BB*VV)

typedef __attribute__((ext_vector_type(8))) short bf16x8;
typedef __attribute__((ext_vector_type(4))) float f32x4;
typedef __attribute__((address_space(1))) const void gv_t;
typedef __attribute__((address_space(3))) void lv_t;

// ---- workspace layout (float offsets) ----
#define WS_SCORE 0          // [B*S]
#define WS_W     25600      // [B*S]
#define WS_CTX   51200      // [64][512]
#define WS_HNEW  83968      // [64][512]
#define WS_G0    116736     // [2048][64] f32 gate partials x4
#define WS_G1    247808
#define WS_G2    378880
#define WS_G3    509952
#define WS_PGEN  641024     // [64]
#define WS_PART  641088     // [64][8][512] ctx partials
#define WS_ABF   903232     // ushort [64][1024] bf16 out_cat
#define WS_AD1   936000     // ushort [64][832]  bf16 [xe|ctx|0pad]
#define WS_AD2   962624     // ushort [64][512]  bf16 h_prev

__device__ __forceinline__ float sigm(float x){ return 1.f/(1.f+__expf(-x)); }
__device__ __forceinline__ float ftanh(float x){
  x = fminf(fmaxf(x,-15.f),15.f);
  float e = __expf(2.f*x);
  return (e-1.f)/(e+1.f);
}
__device__ __forceinline__ unsigned short f2bf(float f){
  unsigned int u = __builtin_bit_cast(unsigned int, f);
  u += 0x7fffu + ((u>>16)&1u);
  return (unsigned short)(u>>16);
}

// ---- software-pipelined MFMA segment (compiler-scheduled; used by k_gates) ----
#define LDW(S, off) { w##S##0 = *(const float4*)(wr + (off)*32); \
                      w##S##1 = *(const float4*)(wr + (off)*32 + 4); }
#define LDA(S, off) { a##S##0 = *(const bf16x8*)(a0 + (off)*32); \
                      a##S##1 = *(const bf16x8*)(a1 + (off)*32); \
                      a##S##2 = *(const bf16x8*)(a2 + (off)*32); \
                      a##S##3 = *(const bf16x8*)(a3 + (off)*32); }
#define CONS(S) { union { bf16x8 v; unsigned int u[4]; } bb_; \
  float4 f0_ = w##S##0; float4 f1_ = w##S##1; \
  asm("v_cvt_pk_bf16_f32 %0, %1, %2" : "=v"(bb_.u[0]) : "v"(f0_.x), "v"(f0_.y)); \
  asm("v_cvt_pk_bf16_f32 %0, %1, %2" : "=v"(bb_.u[1]) : "v"(f0_.z), "v"(f0_.w)); \
  asm("v_cvt_pk_bf16_f32 %0, %1, %2" : "=v"(bb_.u[2]) : "v"(f1_.x), "v"(f1_.y)); \
  asm("v_cvt_pk_bf16_f32 %0, %1, %2" : "=v"(bb_.u[3]) : "v"(f1_.z), "v"(f1_.w)); \
  acc0 = __builtin_amdgcn_mfma_f32_16x16x32_bf16(a##S##0, bb_.v, acc0, 0,0,0); \
  acc1 = __builtin_amdgcn_mfma_f32_16x16x32_bf16(a##S##1, bb_.v, acc1, 0,0,0); \
  acc2 = __builtin_amdgcn_mfma_f32_16x16x32_bf16(a##S##2, bb_.v, acc2, 0,0,0); \
  acc3 = __builtin_amdgcn_mfma_f32_16x16x32_bf16(a##S##3, bb_.v, acc3, 0,0,0); }

// depth-2 pipeline, NSTEP % 2 == 0 (k_gates)
template<int NSTEP>
__device__ __forceinline__ void mfma_seg2(const float* __restrict__ wr,
    const unsigned short* __restrict__ a0, const unsigned short* __restrict__ a1,
    const unsigned short* __restrict__ a2, const unsigned short* __restrict__ a3,
    f32x4& acc0, f32x4& acc1, f32x4& acc2, f32x4& acc3)
{
  static_assert(NSTEP % 2 == 0 && NSTEP >= 4, "");
  float4 wA0,wA1, wB0,wB1;
  bf16x8 aA0,aA1,aA2,aA3, aB0,aB1,aB2,aB3;
  LDW(A,0) LDA(A,0)
  LDW(B,1) LDA(B,1)
  #pragma unroll
  for (int ks=0; ks<NSTEP; ks+=2){
    CONS(A) if (ks+2 < NSTEP){ LDW(A,ks+2) LDA(A,ks+2) }
    CONS(B) if (ks+3 < NSTEP){ LDW(B,ks+3) LDA(B,ks+3) }
  }
}

// K0: build bf16 activation buffers: ad1 = [xe(300) | ctx(later) | 0-pad(20)], ad2 = h_prev
__global__ __launch_bounds__(256) void k_prep(const int* __restrict__ x,
    const float* __restrict__ emb, const float* __restrict__ h0,
    unsigned short* __restrict__ ad1, unsigned short* __restrict__ ad2)
{
  int n = blockIdx.x*256 + threadIdx.x;     // 336 blocks: 53248 + 32768
  if (n < BB*832){
    int b = n/832, k = n - b*832;
    if (k < EE) ad1[n] = f2bf(emb[(size_t)x[b]*EE + k]);
    else if (k >= 812) ad1[n] = 0;
  } else {
    int m = n - BB*832;
    ad2[m] = f2bf(h0[m]);
  }
}

// K1: score[b,s] = V_w . tanh(enc[b,s,:] + h_prev[b,:]) + V_b
__global__ __launch_bounds__(256) void k_score(const float* __restrict__ enc,
    const float* __restrict__ h0, const float* __restrict__ Vw,
    const float* __restrict__ Vb, float* __restrict__ score)
{
  int wv = threadIdx.x >> 6, lane = threadIdx.x & 63;
  int pair = blockIdx.x*4 + wv;
  int b = pair / SS;
  int i0 = lane*8;
  const float4* ep = (const float4*)(enc + (size_t)pair*HH + i0);
  const float4* hp = (const float4*)(h0 + b*HH + i0);
  const float4* vp = (const float4*)(Vw + i0);
  float4 e0 = ep[0], e1 = ep[1];
  float4 hv0 = hp[0], hv1 = hp[1];
  float4 v0 = vp[0], v1 = vp[1];
  float sum = ftanh(e0.x+hv0.x)*v0.x + ftanh(e0.y+hv0.y)*v0.y
            + ftanh(e0.z+hv0.z)*v0.z + ftanh(e0.w+hv0.w)*v0.w
            + ftanh(e1.x+hv1.x)*v1.x + ftanh(e1.y+hv1.y)*v1.y
            + ftanh(e1.z+hv1.z)*v1.z + ftanh(e1.w+hv1.w)*v1.w;
  #pragma unroll
  for (int off=32; off; off>>=1) sum += __shfl_xor(sum, off);
  if (lane==0) score[pair] = sum + Vb[0];
}

// K2: per (b, s-chunk): recompute softmax over full row, partial ctx over 50 s.
__global__ __launch_bounds__(256) void k_ctx(const float* __restrict__ enc,
    const float* __restrict__ score, float* __restrict__ wout,
    float* __restrict__ part)
{
  __shared__ float red[256];
  __shared__ float wl[SS];
  int b = blockIdx.x >> 3, sp = blockIdx.x & 7;
  int t = threadIdx.x;
  float v1 = score[b*SS + t];
  float v2 = (t < SS-256) ? score[b*SS + t + 256] : -1e30f;
  red[t] = fmaxf(v1, v2);
  __syncthreads();
  for (int o=128; o; o>>=1){ if (t<o) red[t] = fmaxf(red[t], red[t+o]); __syncthreads(); }
  float mx = red[0];
  __syncthreads();
  float e1 = __expf(v1 - mx);
  float e2 = (t < SS-256) ? __expf(v2 - mx) : 0.f;
  red[t] = e1 + e2;
  __syncthreads();
  for (int o=128; o; o>>=1){ if (t<o) red[t] += red[t+o]; __syncthreads(); }
  float inv = 1.f/red[0];
  float w1 = e1*inv;
  wl[t] = w1;
  if (sp==0) wout[b*SS + t] = w1;
  if (t < SS-256){
    float w2 = e2*inv;
    wl[t+256] = w2;
    if (sp==0) wout[b*SS + t + 256] = w2;
  }
  __syncthreads();
  float a0 = 0.f, a1 = 0.f;
  const float* ebase = enc + ((size_t)b*SS + sp*50)*HH + 2*t;
  #pragma unroll 5
  for (int s=0; s<50; ++s){
    float wg = wl[sp*50 + s];
    float2 e = *(const float2*)(ebase + s*HH);
    a0 += wg * e.x;
    a1 += wg * e.y;
  }
  *(float2*)(part + (size_t)(b*8+sp)*HH + 2*t) = make_float2(a0, a1);
}

// K3: reduce 8 ctx partials -> ctx f32 + ad1 ctx slice (bf16)
__global__ __launch_bounds__(256) void k_ctx_reduce(const float* __restrict__ part,
    float* __restrict__ ctx, unsigned short* __restrict__ ad1)
{
  int b = blockIdx.x, t = threadIdx.x;
  float a0=0.f, a1=0.f;
  #pragma unroll
  for (int sp=0; sp<8; ++sp){
    float2 e = *(const float2*)(part + (size_t)(b*8+sp)*HH + 2*t);
    a0 += e.x; a1 += e.y;
  }
  *(float2*)(ctx + b*HH + 2*t) = make_float2(a0, a1);
  ad1[b*832 + EE + 2*t]     = f2bf(a0);
  ad1[b*832 + EE + 2*t + 1] = f2bf(a1);
}

// K4: gates via MFMA. 512 wave-tiles = 128 j-tiles x 4 K-parts (12/14/8/8 steps).
__global__ __launch_bounds__(128, 4) void k_gates(const float* __restrict__ Wih,
    const float* __restrict__ Whh, const unsigned short* __restrict__ ad1,
    const unsigned short* __restrict__ ad2,
    float* __restrict__ g0, float* __restrict__ g1,
    float* __restrict__ g2, float* __restrict__ g3)
{
  int wt = blockIdx.x*2 + (threadIdx.x >> 6);   // 0..511
  int lane = threadIdx.x & 63;
  int col = lane & 15, kg = lane >> 4;
  int jt = wt >> 2, part = wt & 3;
  int j = jt*16 + col;
  f32x4 acc0={0.f,0.f,0.f,0.f}, acc1=acc0, acc2=acc0, acc3=acc0;
  float* g;
  if (part < 2){
    int k0 = part ? 384 : 0;
    const float* wr = Wih + (size_t)j*KD + k0 + kg*8;
    const unsigned short* a = ad1 + col*832 + k0 + kg*8;
    if (part) mfma_seg2<14>(wr, a, a+16*832, a+32*832, a+48*832, acc0,acc1,acc2,acc3);
    else      mfma_seg2<12>(wr, a, a+16*832, a+32*832, a+48*832, acc0,acc1,acc2,acc3);
    g = part ? g1 : g0;
  } else {
    int k0 = (part==3) ? 256 : 0;
    const float* wr = Whh + (size_t)j*HH + k0 + kg*8;
    const unsigned short* a = ad2 + col*512 + k0 + kg*8;
    mfma_seg2<8>(wr, a, a+16*512, a+32*512, a+48*512, acc0,acc1,acc2,acc3);
    g = (part==3) ? g3 : g2;
  }
  #pragma unroll
  for (int i=0;i<4;i++){
    g[(size_t)j*BB + 0*16 + kg*4 + i] = acc0[i];
    g[(size_t)j*BB + 1*16 + kg*4 + i] = acc1[i];
    g[(size_t)j*BB + 2*16 + kg*4 + i] = acc2[i];
    g[(size_t)j*BB + 3*16 + kg*4 + i] = acc3[i];
  }
}

// K5: LSTM cell elementwise
__global__ __launch_bounds__(256) void k_lstm(const float* __restrict__ c0,
    const float* __restrict__ bih, const float* __restrict__ bhh,
    const float* __restrict__ g0, const float* __restrict__ g1,
    const float* __restrict__ g2, const float* __restrict__ g3,
    const float* __restrict__ ctx, float* __restrict__ hnew,
    unsigned short* __restrict__ abf, float* __restrict__ out)
{
  int n = blockIdx.x*256 + threadIdx.x;   // < 32768
  int b = n & 63, h = n >> 6;
  #define GSUM(off) (g0[(off)*BB+b] + g1[(off)*BB+b] + g2[(off)*BB+b] + g3[(off)*BB+b] + bih[off] + bhh[off])
  float gi = GSUM(h);
  float gf = GSUM(HH+h);
  float gg = GSUM(2*HH+h);
  float go = GSUM(3*HH+h);
  #undef GSUM
  float cn = sigm(gf)*c0[b*HH+h] + sigm(gi)*ftanh(gg);
  float hn = sigm(go)*ftanh(cn);
  out[BV + b*HH + h]          = hn;
  out[BV + BB*HH + b*HH + h]  = cn;
  hnew[b*HH + h] = hn;
  abf[b*KC + h]      = f2bf(hn);
  abf[b*KC + HH + h] = f2bf(ctx[b*HH + h]);
}

// K6: p_gen[b] = sigmoid(gen_w . [ctx, h_new, xe] + gen_b)
__global__ __launch_bounds__(256) void k_pgen(const float* __restrict__ genw,
    const float* __restrict__ genb, const float* __restrict__ ctx,
    const float* __restrict__ hnew, const int* __restrict__ x,
    const float* __restrict__ emb, float* __restrict__ pgen)
{
  __shared__ float red[256];
  int b = blockIdx.x, t = threadIdx.x;
  float p = 0.f;
  for (int k=t; k<KG; k+=256){
    float g = genw[k];
    float v = (k < HH) ? ctx[b*HH + k]
            : (k < 2*HH) ? hnew[b*HH + k - HH]
            : emb[(size_t)x[b]*EE + (k - 2*HH)];
    p += g*v;
  }
  red[t] = p; __syncthreads();
  for (int o=128; o; o>>=1){ if (t<o) red[t] += red[t+o]; __syncthreads(); }
  if (t==0) pgen[b] = sigm(red[0] + genb[0]);
}

// K7 v10: block-streaming GEMM. Block = 512 thr (8 waves) owns a 16-row
// weight tile = ONE CONTIGUOUS 64 KB of out_w, DMA'd via global_load_lds
// (width 16) into row-padded LDS (+16 B/row vs bank conflicts). Exactly one
// vmcnt(0)+barrier drain per block, amortized over 64 KB. Waves: 4 M-tiles
// x 2 K-halves; A preloaded to 16 bf16x8 regs; halves combined via LDS.
#define PADB 4112   // padded row stride in bytes (4096 + 16)
__global__ __launch_bounds__(512, 4) void k_gemm(const float* __restrict__ out_w,
    const float* __restrict__ out_b, const unsigned short* __restrict__ abf,
    const float* __restrict__ pgen, float* __restrict__ out)
{
  __shared__ __align__(16) char wlds[16*PADB];   // 65792 B
  __shared__ float comb[4][16][17];               // 4352 B
  int t = threadIdx.x;
  int w = t >> 6, lane = t & 63;
  int col = lane & 15, kg = lane >> 4;
  int vt = blockIdx.x;                            // 0..3124
  int mt = w >> 1, kh = w & 1;
  const char* wbase = (const char*)(out_w + (size_t)vt*16*KC);

  // stage 64 KB: wave w DMAs chunks c = w*8+i (1 KB each, contiguous source)
  #pragma unroll
  for (int i=0;i<8;i++){
    int c = w*8 + i;
    int r = c >> 2, q = c & 3;
    const char* gp = wbase + r*4096 + q*1024 + lane*16;
    __builtin_amdgcn_global_load_lds((gv_t*)gp, (lv_t*)(wlds + r*PADB + q*1024), 16, 0, 0);
  }

  // preload A-fragments (this wave's M-tile x K-half) into registers
  const unsigned short* ap = abf + (size_t)(mt*16 + col)*KC + kh*512 + kg*8;
  bf16x8 pa[16];
  #pragma unroll
  for (int ks=0; ks<16; ++ks) pa[ks] = *(const bf16x8*)(ap + ks*32);

  __syncthreads();   // drains staging DMA + preloads (once per block)

  const char* rb = wlds + col*PADB + kh*2048 + kg*32;
  f32x4 acc = {0.f,0.f,0.f,0.f};
  #pragma unroll
  for (int ks=0; ks<16; ++ks){
    float4 f0 = *(const float4*)(rb + ks*128);
    float4 f1 = *(const float4*)(rb + ks*128 + 16);
    union { bf16x8 v; unsigned int u[4]; } bb;
    asm("v_cvt_pk_bf16_f32 %0, %1, %2" : "=v"(bb.u[0]) : "v"(f0.x), "v"(f0.y));
    asm("v_cvt_pk_bf16_f32 %0, %1, %2" : "=v"(bb.u[1]) : "v"(f0.z), "v"(f0.w));
    asm("v_cvt_pk_bf16_f32 %0, %1, %2" : "=v"(bb.u[2]) : "v"(f1.x), "v"(f1.y));
    asm("v_cvt_pk_bf16_f32 %0, %1, %2" : "=v"(bb.u[3]) : "v"(f1.z), "v"(f1.w));
    acc = __builtin_amdgcn_mfma_f32_16x16x32_bf16(pa[ks], bb.v, acc, 0,0,0);
  }

  if (kh == 1){
    #pragma unroll
    for (int i=0;i<4;i++) comb[mt][kg*4 + i][col] = acc[i];
  }
  __syncthreads();
  if (kh == 0){
    int v = vt*16 + col;
    float ob = out_b[v];
    #pragma unroll
    for (int i=0;i<4;i++){
      int b = mt*16 + kg*4 + i;
      out[(size_t)b*VV + v] = pgen[b]*(acc[i] + comb[mt][kg*4 + i][col] + ob);
    }
  }
}

// K8: pointer scatter, last-duplicate-wins; text row staged in LDS, branch-free scan.
__global__ __launch_bounds__(256) void k_scatter(const int* __restrict__ text,
    const float* __restrict__ w, const float* __restrict__ pgen,
    float* __restrict__ out)
{
  __shared__ int ts[SS];
  int b = blockIdx.x, t = threadIdx.x;
  ts[t] = text[b*SS + t];
  if (t + 256 < SS) ts[t+256] = text[b*SS + t + 256];
  __syncthreads();
  float pp = 1.f - pgen[b];
  #pragma unroll
  for (int rep=0; rep<2; ++rep){
    int s = t + rep*256;
    if (s < SS){
      int v = ts[s];
      bool dup = false;
      #pragma unroll 4
      for (int s2=s+1; s2<SS; ++s2) dup = dup || (ts[s2]==v);
      if (!dup) out[(size_t)b*VV + v] += pp * w[b*SS + s];
    }
  }
}

extern "C" void kernel_launch(void* const* d_in, const int* in_sizes, int n_in,
                              void* d_out, int out_size, void* d_ws, size_t ws_size,
                              hipStream_t stream)
{
  const int*   x    = (const int*)  d_in[0];
  const float* enc  = (const float*)d_in[1];
  const float* h0   = (const float*)d_in[2];
  const float* c0   = (const float*)d_in[3];
  const int*   text = (const int*)  d_in[4];
  const float* emb  = (const float*)d_in[6];
  const float* Vw   = (const float*)d_in[7];
  const float* Vb   = (const float*)d_in[8];
  const float* genw = (const float*)d_in[9];
  const float* genb = (const float*)d_in[10];
  const float* outw = (const float*)d_in[11];
  const float* outb = (const float*)d_in[12];
  const float* Wih  = (const float*)d_in[13];
  const float* Whh  = (const float*)d_in[14];
  const float* bih  = (const float*)d_in[15];
  const float* bhh  = (const float*)d_in[16];
  float* out = (float*)d_out;

  float* ws     = (float*)d_ws;
  float* score  = ws + WS_SCORE;
  float* wbuf   = ws + WS_W;
  float* ctx    = ws + WS_CTX;
  float* hnew   = ws + WS_HNEW;
  float* g0     = ws + WS_G0;
  float* g1     = ws + WS_G1;
  float* g2     = ws + WS_G2;
  float* g3     = ws + WS_G3;
  float* pgen   = ws + WS_PGEN;
  float* part   = ws + WS_PART;
  unsigned short* abf = (unsigned short*)(ws + WS_ABF);
  unsigned short* ad1 = (unsigned short*)(ws + WS_AD1);
  unsigned short* ad2 = (unsigned short*)(ws + WS_AD2);

  k_prep<<<336, 256, 0, stream>>>(x, emb, h0, ad1, ad2);
  k_score<<<6400, 256, 0, stream>>>(enc, h0, Vw, Vb, score);
  k_ctx<<<512, 256, 0, stream>>>(enc, score, wbuf, part);
  k_ctx_reduce<<<64, 256, 0, stream>>>(part, ctx, ad1);
  k_gates<<<256, 128, 0, stream>>>(Wih, Whh, ad1, ad2, g0, g1, g2, g3);
  k_lstm<<<128, 256, 0, stream>>>(c0, bih, bhh, g0, g1, g2, g3, ctx, hnew, abf, out);
  k_pgen<<<64, 256, 0, stream>>>(genw, genb, ctx, hnew, x, emb, pgen);
  k_gemm<<<3125, 512, 0, stream>>>(outw, outb, abf, pgen, out);
  k_scatter<<<64, 256, 0, stream>>>(text, wbuf, pgen, out);
}

// Round 11
// 143.351 us; speedup vs baseline: 6.1046x; 1.0059x over previous
//
#include <hip/hip_runtime.h>
#include <hip/hip_bf16.h>

#define BB 64
#define SS 400
#define HH 512
#define EE 300
#define VV 50000
#define KD 812     // E+H (LSTM input width)
#define KG 1324    // 2H+E (gen_in width)
#define KC 1024    // 2H (out_cat width)
#define BV (BB*VV)

typedef __attribute__((ext_vector_type(8))) short bf16x8;
typedef __attribute__((ext_vector_type(4))) float f32x4;

// ---- workspace layout (float offsets) ----
#define WS_SCORE 0          // [B*S]
#define WS_W     25600      // [B*S]
#define WS_CTX   51200      // [64][512]
#define WS_HNEW  83968      // [64][512]
#define WS_G0    116736     // [2048][64] f32 gate partials x4
#define WS_G1    247808
#define WS_G2    378880
#define WS_G3    509952
#define WS_PGEN  641024     // [64]
#define WS_PART  641088     // [64][8][512] ctx partials
#define WS_ABF   903232     // ushort [64][1024] bf16 out_cat
#define WS_AD1   936000     // ushort [64][832]  bf16 [xe|ctx|0pad]
#define WS_AD2   962624     // ushort [64][512]  bf16 h_prev

__device__ __forceinline__ float sigm(float x){ return 1.f/(1.f+__expf(-x)); }
__device__ __forceinline__ float ftanh(float x){
  x = fminf(fmaxf(x,-15.f),15.f);
  float e = __expf(2.f*x);
  return (e-1.f)/(e+1.f);
}
__device__ __forceinline__ unsigned short f2bf(float f){
  unsigned int u = __builtin_bit_cast(unsigned int, f);
  u += 0x7fffu + ((u>>16)&1u);
  return (unsigned short)(u>>16);
}

// ---- software-pipelined MFMA segment (compiler-scheduled; used by k_gates) ----
#define LDW(S, off) { w##S##0 = *(const float4*)(wr + (off)*32); \
                      w##S##1 = *(const float4*)(wr + (off)*32 + 4); }
#define LDA(S, off) { a##S##0 = *(const bf16x8*)(a0 + (off)*32); \
                      a##S##1 = *(const bf16x8*)(a1 + (off)*32); \
                      a##S##2 = *(const bf16x8*)(a2 + (off)*32); \
                      a##S##3 = *(const bf16x8*)(a3 + (off)*32); }
#define CONS(S) { union { bf16x8 v; unsigned int u[4]; } bb_; \
  float4 f0_ = w##S##0; float4 f1_ = w##S##1; \
  asm("v_cvt_pk_bf16_f32 %0, %1, %2" : "=v"(bb_.u[0]) : "v"(f0_.x), "v"(f0_.y)); \
  asm("v_cvt_pk_bf16_f32 %0, %1, %2" : "=v"(bb_.u[1]) : "v"(f0_.z), "v"(f0_.w)); \
  asm("v_cvt_pk_bf16_f32 %0, %1, %2" : "=v"(bb_.u[2]) : "v"(f1_.x), "v"(f1_.y)); \
  asm("v_cvt_pk_bf16_f32 %0, %1, %2" : "=v"(bb_.u[3]) : "v"(f1_.z), "v"(f1_.w)); \
  acc0 = __builtin_amdgcn_mfma_f32_16x16x32_bf16(a##S##0, bb_.v, acc0, 0,0,0); \
  acc1 = __builtin_amdgcn_mfma_f32_16x16x32_bf16(a##S##1, bb_.v, acc1, 0,0,0); \
  acc2 = __builtin_amdgcn_mfma_f32_16x16x32_bf16(a##S##2, bb_.v, acc2, 0,0,0); \
  acc3 = __builtin_amdgcn_mfma_f32_16x16x32_bf16(a##S##3, bb_.v, acc3, 0,0,0); }

// depth-2 pipeline, NSTEP % 2 == 0 (k_gates)
template<int NSTEP>
__device__ __forceinline__ void mfma_seg2(const float* __restrict__ wr,
    const unsigned short* __restrict__ a0, const unsigned short* __restrict__ a1,
    const unsigned short* __restrict__ a2, const unsigned short* __restrict__ a3,
    f32x4& acc0, f32x4& acc1, f32x4& acc2, f32x4& acc3)
{
  static_assert(NSTEP % 2 == 0 && NSTEP >= 4, "");
  float4 wA0,wA1, wB0,wB1;
  bf16x8 aA0,aA1,aA2,aA3, aB0,aB1,aB2,aB3;
  LDW(A,0) LDA(A,0)
  LDW(B,1) LDA(B,1)
  #pragma unroll
  for (int ks=0; ks<NSTEP; ks+=2){
    CONS(A) if (ks+2 < NSTEP){ LDW(A,ks+2) LDA(A,ks+2) }
    CONS(B) if (ks+3 < NSTEP){ LDW(B,ks+3) LDA(B,ks+3) }
  }
}

// K0: build bf16 activation buffers: ad1 = [xe(300) | ctx(later) | 0-pad(20)], ad2 = h_prev
__global__ __launch_bounds__(256) void k_prep(const int* __restrict__ x,
    const float* __restrict__ emb, const float* __restrict__ h0,
    unsigned short* __restrict__ ad1, unsigned short* __restrict__ ad2)
{
  int n = blockIdx.x*256 + threadIdx.x;     // 336 blocks: 53248 + 32768
  if (n < BB*832){
    int b = n/832, k = n - b*832;
    if (k < EE) ad1[n] = f2bf(emb[(size_t)x[b]*EE + k]);
    else if (k >= 812) ad1[n] = 0;
  } else {
    int m = n - BB*832;
    ad2[m] = f2bf(h0[m]);
  }
}

// K1: score[b,s] = V_w . tanh(enc[b,s,:] + h_prev[b,:]) + V_b
__global__ __launch_bounds__(256) void k_score(const float* __restrict__ enc,
    const float* __restrict__ h0, const float* __restrict__ Vw,
    const float* __restrict__ Vb, float* __restrict__ score)
{
  int wv = threadIdx.x >> 6, lane = threadIdx.x & 63;
  int pair = blockIdx.x*4 + wv;
  int b = pair / SS;
  int i0 = lane*8;
  const float4* ep = (const float4*)(enc + (size_t)pair*HH + i0);
  const float4* hp = (const float4*)(h0 + b*HH + i0);
  const float4* vp = (const float4*)(Vw + i0);
  float4 e0 = ep[0], e1 = ep[1];
  float4 hv0 = hp[0], hv1 = hp[1];
  float4 v0 = vp[0], v1 = vp[1];
  float sum = ftanh(e0.x+hv0.x)*v0.x + ftanh(e0.y+hv0.y)*v0.y
            + ftanh(e0.z+hv0.z)*v0.z + ftanh(e0.w+hv0.w)*v0.w
            + ftanh(e1.x+hv1.x)*v1.x + ftanh(e1.y+hv1.y)*v1.y
            + ftanh(e1.z+hv1.z)*v1.z + ftanh(e1.w+hv1.w)*v1.w;
  #pragma unroll
  for (int off=32; off; off>>=1) sum += __shfl_xor(sum, off);
  if (lane==0) score[pair] = sum + Vb[0];
}

// K2: per (b, s-chunk): recompute softmax over full row, partial ctx over 50 s.
__global__ __launch_bounds__(256) void k_ctx(const float* __restrict__ enc,
    const float* __restrict__ score, float* __restrict__ wout,
    float* __restrict__ part)
{
  __shared__ float red[256];
  __shared__ float wl[SS];
  int b = blockIdx.x >> 3, sp = blockIdx.x & 7;
  int t = threadIdx.x;
  float v1 = score[b*SS + t];
  float v2 = (t < SS-256) ? score[b*SS + t + 256] : -1e30f;
  red[t] = fmaxf(v1, v2);
  __syncthreads();
  for (int o=128; o; o>>=1){ if (t<o) red[t] = fmaxf(red[t], red[t+o]); __syncthreads(); }
  float mx = red[0];
  __syncthreads();
  float e1 = __expf(v1 - mx);
  float e2 = (t < SS-256) ? __expf(v2 - mx) : 0.f;
  red[t] = e1 + e2;
  __syncthreads();
  for (int o=128; o; o>>=1){ if (t<o) red[t] += red[t+o]; __syncthreads(); }
  float inv = 1.f/red[0];
  float w1 = e1*inv;
  wl[t] = w1;
  if (sp==0) wout[b*SS + t] = w1;
  if (t < SS-256){
    float w2 = e2*inv;
    wl[t+256] = w2;
    if (sp==0) wout[b*SS + t + 256] = w2;
  }
  __syncthreads();
  float a0 = 0.f, a1 = 0.f;
  const float* ebase = enc + ((size_t)b*SS + sp*50)*HH + 2*t;
  #pragma unroll 5
  for (int s=0; s<50; ++s){
    float wg = wl[sp*50 + s];
    float2 e = *(const float2*)(ebase + s*HH);
    a0 += wg * e.x;
    a1 += wg * e.y;
  }
  *(float2*)(part + (size_t)(b*8+sp)*HH + 2*t) = make_float2(a0, a1);
}

// K3: reduce 8 ctx partials -> ctx f32 + ad1 ctx slice (bf16)
__global__ __launch_bounds__(256) void k_ctx_reduce(const float* __restrict__ part,
    float* __restrict__ ctx, unsigned short* __restrict__ ad1)
{
  int b = blockIdx.x, t = threadIdx.x;
  float a0=0.f, a1=0.f;
  #pragma unroll
  for (int sp=0; sp<8; ++sp){
    float2 e = *(const float2*)(part + (size_t)(b*8+sp)*HH + 2*t);
    a0 += e.x; a1 += e.y;
  }
  *(float2*)(ctx + b*HH + 2*t) = make_float2(a0, a1);
  ad1[b*832 + EE + 2*t]     = f2bf(a0);
  ad1[b*832 + EE + 2*t + 1] = f2bf(a1);
}

// K4: gates via MFMA. 512 wave-tiles = 128 j-tiles x 4 K-parts (12/14/8/8 steps).
__global__ __launch_bounds__(128, 4) void k_gates(const float* __restrict__ Wih,
    const float* __restrict__ Whh, const unsigned short* __restrict__ ad1,
    const unsigned short* __restrict__ ad2,
    float* __restrict__ g0, float* __restrict__ g1,
    float* __restrict__ g2, float* __restrict__ g3)
{
  int wt = blockIdx.x*2 + (threadIdx.x >> 6);   // 0..511
  int lane = threadIdx.x & 63;
  int col = lane & 15, kg = lane >> 4;
  int jt = wt >> 2, part = wt & 3;
  int j = jt*16 + col;
  f32x4 acc0={0.f,0.f,0.f,0.f}, acc1=acc0, acc2=acc0, acc3=acc0;
  float* g;
  if (part < 2){
    int k0 = part ? 384 : 0;
    const float* wr = Wih + (size_t)j*KD + k0 + kg*8;
    const unsigned short* a = ad1 + col*832 + k0 + kg*8;
    if (part) mfma_seg2<14>(wr, a, a+16*832, a+32*832, a+48*832, acc0,acc1,acc2,acc3);
    else      mfma_seg2<12>(wr, a, a+16*832, a+32*832, a+48*832, acc0,acc1,acc2,acc3);
    g = part ? g1 : g0;
  } else {
    int k0 = (part==3) ? 256 : 0;
    const float* wr = Whh + (size_t)j*HH + k0 + kg*8;
    const unsigned short* a = ad2 + col*512 + k0 + kg*8;
    mfma_seg2<8>(wr, a, a+16*512, a+32*512, a+48*512, acc0,acc1,acc2,acc3);
    g = (part==3) ? g3 : g2;
  }
  #pragma unroll
  for (int i=0;i<4;i++){
    g[(size_t)j*BB + 0*16 + kg*4 + i] = acc0[i];
    g[(size_t)j*BB + 1*16 + kg*4 + i] = acc1[i];
    g[(size_t)j*BB + 2*16 + kg*4 + i] = acc2[i];
    g[(size_t)j*BB + 3*16 + kg*4 + i] = acc3[i];
  }
}

// K5: LSTM cell elementwise
__global__ __launch_bounds__(256) void k_lstm(const float* __restrict__ c0,
    const float* __restrict__ bih, const float* __restrict__ bhh,
    const float* __restrict__ g0, const float* __restrict__ g1,
    const float* __restrict__ g2, const float* __restrict__ g3,
    const float* __restrict__ ctx, float* __restrict__ hnew,
    unsigned short* __restrict__ abf, float* __restrict__ out)
{
  int n = blockIdx.x*256 + threadIdx.x;   // < 32768
  int b = n & 63, h = n >> 6;
  #define GSUM(off) (g0[(off)*BB+b] + g1[(off)*BB+b] + g2[(off)*BB+b] + g3[(off)*BB+b] + bih[off] + bhh[off])
  float gi = GSUM(h);
  float gf = GSUM(HH+h);
  float gg = GSUM(2*HH+h);
  float go = GSUM(3*HH+h);
  #undef GSUM
  float cn = sigm(gf)*c0[b*HH+h] + sigm(gi)*ftanh(gg);
  float hn = sigm(go)*ftanh(cn);
  out[BV + b*HH + h]          = hn;
  out[BV + BB*HH + b*HH + h]  = cn;
  hnew[b*HH + h] = hn;
  abf[b*KC + h]      = f2bf(hn);
  abf[b*KC + HH + h] = f2bf(ctx[b*HH + h]);
}

// K6: p_gen[b] = sigmoid(gen_w . [ctx, h_new, xe] + gen_b)
__global__ __launch_bounds__(256) void k_pgen(const float* __restrict__ genw,
    const float* __restrict__ genb, const float* __restrict__ ctx,
    const float* __restrict__ hnew, const int* __restrict__ x,
    const float* __restrict__ emb, float* __restrict__ pgen)
{
  __shared__ float red[256];
  int b = blockIdx.x, t = threadIdx.x;
  float p = 0.f;
  for (int k=t; k<KG; k+=256){
    float g = genw[k];
    float v = (k < HH) ? ctx[b*HH + k]
            : (k < 2*HH) ? hnew[b*HH + k - HH]
            : emb[(size_t)x[b]*EE + (k - 2*HH)];
    p += g*v;
  }
  red[t] = p; __syncthreads();
  for (int o=128; o; o>>=1){ if (t<o) red[t] += red[t+o]; __syncthreads(); }
  if (t==0) pgen[b] = sigm(red[0] + genb[0]);
}

// K7 v11: block-streaming GEMM, REG-STAGED (HK pattern). Block = 512 thr owns
// a contiguous 64 KB weight tile; each wave issues 8 contiguous
// global_load_dwordx4 (1 KB each, deep VMEM-to-VGPR queue), A-preload hides
// the latency, then ds_write_b128 into padded LDS. One barrier; compute as R10.
#define PADB 4112   // padded row stride in bytes (4096 + 16) — balanced banks
__global__ __launch_bounds__(512, 2) void k_gemm(const float* __restrict__ out_w,
    const float* __restrict__ out_b, const unsigned short* __restrict__ abf,
    const float* __restrict__ pgen, float* __restrict__ out)
{
  __shared__ __align__(16) char wlds[16*PADB];   // 65792 B
  __shared__ float comb[4][16][17];               // 4352 B
  int t = threadIdx.x;
  int w = t >> 6, lane = t & 63;
  int col = lane & 15, kg = lane >> 4;
  int vt = blockIdx.x;                            // 0..3124
  int mt = w >> 1, kh = w & 1;
  const char* wbase = (const char*)(out_w + (size_t)vt*16*KC);

  // issue 8 contiguous 1 KB loads (wave w covers rows 2w, 2w+1)
  float4 st0,st1,st2,st3,st4,st5,st6,st7;
  {
    const char* gp = wbase + (w*2)*4096 + lane*16;
    st0 = *(const float4*)(gp);
    st1 = *(const float4*)(gp + 1024);
    st2 = *(const float4*)(gp + 2048);
    st3 = *(const float4*)(gp + 3072);
    st4 = *(const float4*)(gp + 4096);
    st5 = *(const float4*)(gp + 5120);
    st6 = *(const float4*)(gp + 6144);
    st7 = *(const float4*)(gp + 7168);
  }

  // A-preload (L2-hot ws) overlaps the weight-load latency
  const unsigned short* ap = abf + (size_t)(mt*16 + col)*KC + kh*512 + kg*8;
  bf16x8 pa[16];
  #pragma unroll
  for (int ks=0; ks<16; ++ks) pa[ks] = *(const bf16x8*)(ap + ks*32);

  // LDS writes (compiler inserts counted vmcnt per dependency)
  {
    char* lp = wlds + (w*2)*PADB + lane*16;
    *(float4*)(lp)            = st0;
    *(float4*)(lp + 1024)     = st1;
    *(float4*)(lp + 2048)     = st2;
    *(float4*)(lp + 3072)     = st3;
    *(float4*)(lp + PADB)     = st4;
    *(float4*)(lp + PADB+1024)= st5;
    *(float4*)(lp + PADB+2048)= st6;
    *(float4*)(lp + PADB+3072)= st7;
  }
  __syncthreads();

  const char* rb = wlds + col*PADB + kh*2048 + kg*32;
  f32x4 acc = {0.f,0.f,0.f,0.f};
  #pragma unroll
  for (int ks=0; ks<16; ++ks){
    float4 f0 = *(const float4*)(rb + ks*128);
    float4 f1 = *(const float4*)(rb + ks*128 + 16);
    union { bf16x8 v; unsigned int u[4]; } bb;
    asm("v_cvt_pk_bf16_f32 %0, %1, %2" : "=v"(bb.u[0]) : "v"(f0.x), "v"(f0.y));
    asm("v_cvt_pk_bf16_f32 %0, %1, %2" : "=v"(bb.u[1]) : "v"(f0.z), "v"(f0.w));
    asm("v_cvt_pk_bf16_f32 %0, %1, %2" : "=v"(bb.u[2]) : "v"(f1.x), "v"(f1.y));
    asm("v_cvt_pk_bf16_f32 %0, %1, %2" : "=v"(bb.u[3]) : "v"(f1.z), "v"(f1.w));
    acc = __builtin_amdgcn_mfma_f32_16x16x32_bf16(pa[ks], bb.v, acc, 0,0,0);
  }

  if (kh == 1){
    #pragma unroll
    for (int i=0;i<4;i++) comb[mt][kg*4 + i][col] = acc[i];
  }
  __syncthreads();
  if (kh == 0){
    int v = vt*16 + col;
    float ob = out_b[v];
    #pragma unroll
    for (int i=0;i<4;i++){
      int b = mt*16 + kg*4 + i;
      out[(size_t)b*VV + v] = pgen[b]*(acc[i] + comb[mt][kg*4 + i][col] + ob);
    }
  }
}

// K8: pointer scatter, last-duplicate-wins; text row staged in LDS, branch-free scan.
__global__ __launch_bounds__(256) void k_scatter(const int* __restrict__ text,
    const float* __restrict__ w, const float* __restrict__ pgen,
    float* __restrict__ out)
{
  __shared__ int ts[SS];
  int b = blockIdx.x, t = threadIdx.x;
  ts[t] = text[b*SS + t];
  if (t + 256 < SS) ts[t+256] = text[b*SS + t + 256];
  __syncthreads();
  float pp = 1.f - pgen[b];
  #pragma unroll
  for (int rep=0; rep<2; ++rep){
    int s = t + rep*256;
    if (s < SS){
      int v = ts[s];
      bool dup = false;
      #pragma unroll 4
      for (int s2=s+1; s2<SS; ++s2) dup = dup || (ts[s2]==v);
      if (!dup) out[(size_t)b*VV + v] += pp * w[b*SS + s];
    }
  }
}

extern "C" void kernel_launch(void* const* d_in, const int* in_sizes, int n_in,
                              void* d_out, int out_size, void* d_ws, size_t ws_size,
                              hipStream_t stream)
{
  const int*   x    = (const int*)  d_in[0];
  const float* enc  = (const float*)d_in[1];
  const float* h0   = (const float*)d_in[2];
  const float* c0   = (const float*)d_in[3];
  const int*   text = (const int*)  d_in[4];
  const float* emb  = (const float*)d_in[6];
  const float* Vw   = (const float*)d_in[7];
  const float* Vb   = (const float*)d_in[8];
  const float* genw = (const float*)d_in[9];
  const float* genb = (const float*)d_in[10];
  const float* outw = (const float*)d_in[11];
  const float* outb = (const float*)d_in[12];
  const float* Wih  = (const float*)d_in[13];
  const float* Whh  = (const float*)d_in[14];
  const float* bih  = (const float*)d_in[15];
  const float* bhh  = (const float*)d_in[16];
  float* out = (float*)d_out;

  float* ws     = (float*)d_ws;
  float* score  = ws + WS_SCORE;
  float* wbuf   = ws + WS_W;
  float* ctx    = ws + WS_CTX;
  float* hnew   = ws + WS_HNEW;
  float* g0     = ws + WS_G0;
  float* g1     = ws + WS_G1;
  float* g2     = ws + WS_G2;
  float* g3     = ws + WS_G3;
  float* pgen   = ws + WS_PGEN;
  float* part   = ws + WS_PART;
  unsigned short* abf = (unsigned short*)(ws + WS_ABF);
  unsigned short* ad1 = (unsigned short*)(ws + WS_AD1);
  unsigned short* ad2 = (unsigned short*)(ws + WS_AD2);

  k_prep<<<336, 256, 0, stream>>>(x, emb, h0, ad1, ad2);
  k_score<<<6400, 256, 0, stream>>>(enc, h0, Vw, Vb, score);
  k_ctx<<<512, 256, 0, stream>>>(enc, score, wbuf, part);
  k_ctx_reduce<<<64, 256, 0, stream>>>(part, ctx, ad1);
  k_gates<<<256, 128, 0, stream>>>(Wih, Whh, ad1, ad2, g0, g1, g2, g3);
  k_lstm<<<128, 256, 0, stream>>>(c0, bih, bhh, g0, g1, g2, g3, ctx, hnew, abf, out);
  k_pgen<<<64, 256, 0, stream>>>(genw, genb, ctx, hnew, x, emb, pgen);
  k_gemm<<<3125, 512, 0, stream>>>(outw, outb, abf, pgen, out);
  k_scatter<<<64, 256, 0, stream>>>(text, wbuf, pgen, out);
}

// Round 12
// 129.287 us; speedup vs baseline: 6.7687x; 1.1088x over previous
//
#include <hip/hip_runtime.h>
#include <hip/hip_bf16.h>

#define BB 64
#define SS 400
#define HH 512
#define EE 300
#define VV 50000
#define KD 812     // E+H (LSTM input width)
#define KG 1324    // 2H+E (gen_in width)
#define KC 1024    // 2H (out_cat width)
#define BV (BB*VV)

typedef __attribute__((ext_vector_type(8))) short bf16x8;
typedef __attribute__((ext_vector_type(4))) float f32x4;
typedef __attribute__((address_space(1))) const void gv_t;
typedef __attribute__((address_space(3))) void lv_t;

// ---- workspace layout (float offsets) ----
#define WS_SCORE 0          // [B*S]
#define WS_W     25600      // [B*S]
#define WS_CTX   51200      // [64][512]
#define WS_HNEW  83968      // [64][512]
#define WS_G0    116736     // [2048][64] f32 gate partials x4
#define WS_G1    247808
#define WS_G2    378880
#define WS_G3    509952
#define WS_PGEN  641024     // [64]
#define WS_PART  641088     // [64][8][512] ctx partials
#define WS_ABF   903232     // ushort [64][1024] bf16 out_cat
#define WS_AD1   936000     // ushort [64][832]  bf16 [xe|ctx|0pad]
#define WS_AD2   962624     // ushort [64][512]  bf16 h_prev

__device__ __forceinline__ float sigm(float x){ return 1.f/(1.f+__expf(-x)); }
__device__ __forceinline__ float ftanh(float x){
  x = fminf(fmaxf(x,-15.f),15.f);
  float e = __expf(2.f*x);
  return (e-1.f)/(e+1.f);
}
__device__ __forceinline__ unsigned short f2bf(float f){
  unsigned int u = __builtin_bit_cast(unsigned int, f);
  u += 0x7fffu + ((u>>16)&1u);
  return (unsigned short)(u>>16);
}

// ---- software-pipelined MFMA segment (compiler-scheduled; used by k_gates) ----
#define LDW(S, off) { w##S##0 = *(const float4*)(wr + (off)*32); \
                      w##S##1 = *(const float4*)(wr + (off)*32 + 4); }
#define LDA(S, off) { a##S##0 = *(const bf16x8*)(a0 + (off)*32); \
                      a##S##1 = *(const bf16x8*)(a1 + (off)*32); \
                      a##S##2 = *(const bf16x8*)(a2 + (off)*32); \
                      a##S##3 = *(const bf16x8*)(a3 + (off)*32); }
#define CONS(S) { union { bf16x8 v; unsigned int u[4]; } bb_; \
  float4 f0_ = w##S##0; float4 f1_ = w##S##1; \
  asm("v_cvt_pk_bf16_f32 %0, %1, %2" : "=v"(bb_.u[0]) : "v"(f0_.x), "v"(f0_.y)); \
  asm("v_cvt_pk_bf16_f32 %0, %1, %2" : "=v"(bb_.u[1]) : "v"(f0_.z), "v"(f0_.w)); \
  asm("v_cvt_pk_bf16_f32 %0, %1, %2" : "=v"(bb_.u[2]) : "v"(f1_.x), "v"(f1_.y)); \
  asm("v_cvt_pk_bf16_f32 %0, %1, %2" : "=v"(bb_.u[3]) : "v"(f1_.z), "v"(f1_.w)); \
  acc0 = __builtin_amdgcn_mfma_f32_16x16x32_bf16(a##S##0, bb_.v, acc0, 0,0,0); \
  acc1 = __builtin_amdgcn_mfma_f32_16x16x32_bf16(a##S##1, bb_.v, acc1, 0,0,0); \
  acc2 = __builtin_amdgcn_mfma_f32_16x16x32_bf16(a##S##2, bb_.v, acc2, 0,0,0); \
  acc3 = __builtin_amdgcn_mfma_f32_16x16x32_bf16(a##S##3, bb_.v, acc3, 0,0,0); }

// depth-2 pipeline, NSTEP % 2 == 0 (k_gates)
template<int NSTEP>
__device__ __forceinline__ void mfma_seg2(const float* __restrict__ wr,
    const unsigned short* __restrict__ a0, const unsigned short* __restrict__ a1,
    const unsigned short* __restrict__ a2, const unsigned short* __restrict__ a3,
    f32x4& acc0, f32x4& acc1, f32x4& acc2, f32x4& acc3)
{
  static_assert(NSTEP % 2 == 0 && NSTEP >= 4, "");
  float4 wA0,wA1, wB0,wB1;
  bf16x8 aA0,aA1,aA2,aA3, aB0,aB1,aB2,aB3;
  LDW(A,0) LDA(A,0)
  LDW(B,1) LDA(B,1)
  #pragma unroll
  for (int ks=0; ks<NSTEP; ks+=2){
    CONS(A) if (ks+2 < NSTEP){ LDW(A,ks+2) LDA(A,ks+2) }
    CONS(B) if (ks+3 < NSTEP){ LDW(B,ks+3) LDA(B,ks+3) }
  }
}

// K0: build bf16 activation buffers: ad1 = [xe(300) | ctx(later) | 0-pad(20)], ad2 = h_prev
__global__ __launch_bounds__(256) void k_prep(const int* __restrict__ x,
    const float* __restrict__ emb, const float* __restrict__ h0,
    unsigned short* __restrict__ ad1, unsigned short* __restrict__ ad2)
{
  int n = blockIdx.x*256 + threadIdx.x;     // 336 blocks: 53248 + 32768
  if (n < BB*832){
    int b = n/832, k = n - b*832;
    if (k < EE) ad1[n] = f2bf(emb[(size_t)x[b]*EE + k]);
    else if (k >= 812) ad1[n] = 0;
  } else {
    int m = n - BB*832;
    ad2[m] = f2bf(h0[m]);
  }
}

// K1: score[b,s] = V_w . tanh(enc[b,s,:] + h_prev[b,:]) + V_b
__global__ __launch_bounds__(256) void k_score(const float* __restrict__ enc,
    const float* __restrict__ h0, const float* __restrict__ Vw,
    const float* __restrict__ Vb, float* __restrict__ score)
{
  int wv = threadIdx.x >> 6, lane = threadIdx.x & 63;
  int pair = blockIdx.x*4 + wv;
  int b = pair / SS;
  int i0 = lane*8;
  const float4* ep = (const float4*)(enc + (size_t)pair*HH + i0);
  const float4* hp = (const float4*)(h0 + b*HH + i0);
  const float4* vp = (const float4*)(Vw + i0);
  float4 e0 = ep[0], e1 = ep[1];
  float4 hv0 = hp[0], hv1 = hp[1];
  float4 v0 = vp[0], v1 = vp[1];
  float sum = ftanh(e0.x+hv0.x)*v0.x + ftanh(e0.y+hv0.y)*v0.y
            + ftanh(e0.z+hv0.z)*v0.z + ftanh(e0.w+hv0.w)*v0.w
            + ftanh(e1.x+hv1.x)*v1.x + ftanh(e1.y+hv1.y)*v1.y
            + ftanh(e1.z+hv1.z)*v1.z + ftanh(e1.w+hv1.w)*v1.w;
  #pragma unroll
  for (int off=32; off; off>>=1) sum += __shfl_xor(sum, off);
  if (lane==0) score[pair] = sum + Vb[0];
}

// K2: per (b, s-chunk): recompute softmax over full row, partial ctx over 50 s.
__global__ __launch_bounds__(256) void k_ctx(const float* __restrict__ enc,
    const float* __restrict__ score, float* __restrict__ wout,
    float* __restrict__ part)
{
  __shared__ float red[256];
  __shared__ float wl[SS];
  int b = blockIdx.x >> 3, sp = blockIdx.x & 7;
  int t = threadIdx.x;
  float v1 = score[b*SS + t];
  float v2 = (t < SS-256) ? score[b*SS + t + 256] : -1e30f;
  red[t] = fmaxf(v1, v2);
  __syncthreads();
  for (int o=128; o; o>>=1){ if (t<o) red[t] = fmaxf(red[t], red[t+o]); __syncthreads(); }
  float mx = red[0];
  __syncthreads();
  float e1 = __expf(v1 - mx);
  float e2 = (t < SS-256) ? __expf(v2 - mx) : 0.f;
  red[t] = e1 + e2;
  __syncthreads();
  for (int o=128; o; o>>=1){ if (t<o) red[t] += red[t+o]; __syncthreads(); }
  float inv = 1.f/red[0];
  float w1 = e1*inv;
  wl[t] = w1;
  if (sp==0) wout[b*SS + t] = w1;
  if (t < SS-256){
    float w2 = e2*inv;
    wl[t+256] = w2;
    if (sp==0) wout[b*SS + t + 256] = w2;
  }
  __syncthreads();
  float a0 = 0.f, a1 = 0.f;
  const float* ebase = enc + ((size_t)b*SS + sp*50)*HH + 2*t;
  #pragma unroll 5
  for (int s=0; s<50; ++s){
    float wg = wl[sp*50 + s];
    float2 e = *(const float2*)(ebase + s*HH);
    a0 += wg * e.x;
    a1 += wg * e.y;
  }
  *(float2*)(part + (size_t)(b*8+sp)*HH + 2*t) = make_float2(a0, a1);
}

// K3: reduce 8 ctx partials -> ctx f32 + ad1 ctx slice (bf16)
__global__ __launch_bounds__(256) void k_ctx_reduce(const float* __restrict__ part,
    float* __restrict__ ctx, unsigned short* __restrict__ ad1)
{
  int b = blockIdx.x, t = threadIdx.x;
  float a0=0.f, a1=0.f;
  #pragma unroll
  for (int sp=0; sp<8; ++sp){
    float2 e = *(const float2*)(part + (size_t)(b*8+sp)*HH + 2*t);
    a0 += e.x; a1 += e.y;
  }
  *(float2*)(ctx + b*HH + 2*t) = make_float2(a0, a1);
  ad1[b*832 + EE + 2*t]     = f2bf(a0);
  ad1[b*832 + EE + 2*t + 1] = f2bf(a1);
}

// K4: gates via MFMA. 512 wave-tiles = 128 j-tiles x 4 K-parts (12/14/8/8 steps).
__global__ __launch_bounds__(128, 4) void k_gates(const float* __restrict__ Wih,
    const float* __restrict__ Whh, const unsigned short* __restrict__ ad1,
    const unsigned short* __restrict__ ad2,
    float* __restrict__ g0, float* __restrict__ g1,
    float* __restrict__ g2, float* __restrict__ g3)
{
  int wt = blockIdx.x*2 + (threadIdx.x >> 6);   // 0..511
  int lane = threadIdx.x & 63;
  int col = lane & 15, kg = lane >> 4;
  int jt = wt >> 2, part = wt & 3;
  int j = jt*16 + col;
  f32x4 acc0={0.f,0.f,0.f,0.f}, acc1=acc0, acc2=acc0, acc3=acc0;
  float* g;
  if (part < 2){
    int k0 = part ? 384 : 0;
    const float* wr = Wih + (size_t)j*KD + k0 + kg*8;
    const unsigned short* a = ad1 + col*832 + k0 + kg*8;
    if (part) mfma_seg2<14>(wr, a, a+16*832, a+32*832, a+48*832, acc0,acc1,acc2,acc3);
    else      mfma_seg2<12>(wr, a, a+16*832, a+32*832, a+48*832, acc0,acc1,acc2,acc3);
    g = part ? g1 : g0;
  } else {
    int k0 = (part==3) ? 256 : 0;
    const float* wr = Whh + (size_t)j*HH + k0 + kg*8;
    const unsigned short* a = ad2 + col*512 + k0 + kg*8;
    mfma_seg2<8>(wr, a, a+16*512, a+32*512, a+48*512, acc0,acc1,acc2,acc3);
    g = (part==3) ? g3 : g2;
  }
  #pragma unroll
  for (int i=0;i<4;i++){
    g[(size_t)j*BB + 0*16 + kg*4 + i] = acc0[i];
    g[(size_t)j*BB + 1*16 + kg*4 + i] = acc1[i];
    g[(size_t)j*BB + 2*16 + kg*4 + i] = acc2[i];
    g[(size_t)j*BB + 3*16 + kg*4 + i] = acc3[i];
  }
}

// K5: LSTM cell elementwise
__global__ __launch_bounds__(256) void k_lstm(const float* __restrict__ c0,
    const float* __restrict__ bih, const float* __restrict__ bhh,
    const float* __restrict__ g0, const float* __restrict__ g1,
    const float* __restrict__ g2, const float* __restrict__ g3,
    const float* __restrict__ ctx, float* __restrict__ hnew,
    unsigned short* __restrict__ abf, float* __restrict__ out)
{
  int n = blockIdx.x*256 + threadIdx.x;   // < 32768
  int b = n & 63, h = n >> 6;
  #define GSUM(off) (g0[(off)*BB+b] + g1[(off)*BB+b] + g2[(off)*BB+b] + g3[(off)*BB+b] + bih[off] + bhh[off])
  float gi = GSUM(h);
  float gf = GSUM(HH+h);
  float gg = GSUM(2*HH+h);
  float go = GSUM(3*HH+h);
  #undef GSUM
  float cn = sigm(gf)*c0[b*HH+h] + sigm(gi)*ftanh(gg);
  float hn = sigm(go)*ftanh(cn);
  out[BV + b*HH + h]          = hn;
  out[BV + BB*HH + b*HH + h]  = cn;
  hnew[b*HH + h] = hn;
  abf[b*KC + h]      = f2bf(hn);
  abf[b*KC + HH + h] = f2bf(ctx[b*HH + h]);
}

// K6: p_gen[b] = sigmoid(gen_w . [ctx, h_new, xe] + gen_b)
__global__ __launch_bounds__(256) void k_pgen(const float* __restrict__ genw,
    const float* __restrict__ genb, const float* __restrict__ ctx,
    const float* __restrict__ hnew, const int* __restrict__ x,
    const float* __restrict__ emb, float* __restrict__ pgen)
{
  __shared__ float red[256];
  int b = blockIdx.x, t = threadIdx.x;
  float p = 0.f;
  for (int k=t; k<KG; k+=256){
    float g = genw[k];
    float v = (k < HH) ? ctx[b*HH + k]
            : (k < 2*HH) ? hnew[b*HH + k - HH]
            : emb[(size_t)x[b]*EE + (k - 2*HH)];
    p += g*v;
  }
  red[t] = p; __syncthreads();
  for (int o=128; o; o>>=1){ if (t<o) red[t] += red[t+o]; __syncthreads(); }
  if (t==0) pgen[b] = sigm(red[0] + genb[0]);
}

// K7 v12: persistent multi-tile GEMM with DOUBLE-BUFFERED DMA staging.
// 256 blocks (1/CU), each loops over ~12 contiguous 16-row tiles. Per iter:
// syncthreads drains DMA for buf[cur]; DMA for tile+1 issued into buf[cur^1]
// and stays in flight across the comb-exchange RAW barrier (lgkmcnt-only,
// no vmcnt drain - T4/rule #18). A-fragments loaded once (tile-invariant).
#define PADB 4112   // padded LDS row stride (4096 + 16), bank-balanced
__global__ __launch_bounds__(512, 2) void k_gemm(const float* __restrict__ out_w,
    const float* __restrict__ out_b, const unsigned short* __restrict__ abf,
    const float* __restrict__ pgen, float* __restrict__ out)
{
  __shared__ __align__(16) char wlds[2][16*PADB];   // 2 x 65792 B
  __shared__ float comb[4][16][17];                  // 4352 B
  int t = threadIdx.x;
  int w = t >> 6, lane = t & 63;
  int col = lane & 15, kg = lane >> 4;
  int mt = w >> 1, kh = w & 1;
  int bid = blockIdx.x;
  int ts = (bid * 3125) >> 8;          // contiguous tile range per block
  int te = ((bid + 1) * 3125) >> 8;

  // A-fragments: invariant across tiles, load ONCE
  const unsigned short* ap = abf + (size_t)(mt*16 + col)*KC + kh*512 + kg*8;
  bf16x8 pa[16];
  #pragma unroll
  for (int ks=0; ks<16; ++ks) pa[ks] = *(const bf16x8*)(ap + ks*32);

  #define DMASTAGE(buf_, tile_) { \
    const char* wb_ = (const char*)(out_w + (size_t)(tile_)*16*KC); \
    _Pragma("unroll") \
    for (int i_=0;i_<8;i_++){ \
      int c_ = w*8 + i_; \
      int r_ = c_ >> 2, q_ = c_ & 3; \
      __builtin_amdgcn_global_load_lds( \
        (gv_t*)(wb_ + r_*4096 + q_*1024 + lane*16), \
        (lv_t*)(&wlds[buf_][0] + r_*PADB + q_*1024), 16, 0, 0); \
    } }

  DMASTAGE(0, ts)
  int cur = 0;
  for (int tile = ts; tile < te; ++tile){
    __syncthreads();                         // drains DMA for wlds[cur]
    if (tile + 1 < te) DMASTAGE(cur^1, tile+1)   // next tile in flight

    const char* rb = &wlds[cur][0] + col*PADB + kh*2048 + kg*32;
    f32x4 acc = {0.f,0.f,0.f,0.f};
    #pragma unroll
    for (int ks=0; ks<16; ++ks){
      float4 f0 = *(const float4*)(rb + ks*128);
      float4 f1 = *(const float4*)(rb + ks*128 + 16);
      union { bf16x8 v; unsigned int u[4]; } bb;
      asm("v_cvt_pk_bf16_f32 %0, %1, %2" : "=v"(bb.u[0]) : "v"(f0.x), "v"(f0.y));
      asm("v_cvt_pk_bf16_f32 %0, %1, %2" : "=v"(bb.u[1]) : "v"(f0.z), "v"(f0.w));
      asm("v_cvt_pk_bf16_f32 %0, %1, %2" : "=v"(bb.u[2]) : "v"(f1.x), "v"(f1.y));
      asm("v_cvt_pk_bf16_f32 %0, %1, %2" : "=v"(bb.u[3]) : "v"(f1.z), "v"(f1.w));
      acc = __builtin_amdgcn_mfma_f32_16x16x32_bf16(pa[ks], bb.v, acc, 0,0,0);
    }

    if (kh == 1){
      #pragma unroll
      for (int i=0;i<4;i++) comb[mt][kg*4 + i][col] = acc[i];
    }
    // RAW barrier: orders comb LDS exchange WITHOUT draining vmcnt,
    // so the next tile's DMA stays in flight (T4).
    asm volatile("s_waitcnt lgkmcnt(0)");
    __builtin_amdgcn_sched_barrier(0);
    __builtin_amdgcn_s_barrier();
    __builtin_amdgcn_sched_barrier(0);
    if (kh == 0){
      int v = tile*16 + col;
      float ob = out_b[v];
      #pragma unroll
      for (int i=0;i<4;i++){
        int b = mt*16 + kg*4 + i;
        out[(size_t)b*VV + v] = pgen[b]*(acc[i] + comb[mt][kg*4 + i][col] + ob);
      }
    }
    cur ^= 1;
  }
  #undef DMASTAGE
}

// K8: pointer scatter, last-duplicate-wins; text row staged in LDS, branch-free scan.
__global__ __launch_bounds__(256) void k_scatter(const int* __restrict__ text,
    const float* __restrict__ w, const float* __restrict__ pgen,
    float* __restrict__ out)
{
  __shared__ int ts[SS];
  int b = blockIdx.x, t = threadIdx.x;
  ts[t] = text[b*SS + t];
  if (t + 256 < SS) ts[t+256] = text[b*SS + t + 256];
  __syncthreads();
  float pp = 1.f - pgen[b];
  #pragma unroll
  for (int rep=0; rep<2; ++rep){
    int s = t + rep*256;
    if (s < SS){
      int v = ts[s];
      bool dup = false;
      #pragma unroll 4
      for (int s2=s+1; s2<SS; ++s2) dup = dup || (ts[s2]==v);
      if (!dup) out[(size_t)b*VV + v] += pp * w[b*SS + s];
    }
  }
}

extern "C" void kernel_launch(void* const* d_in, const int* in_sizes, int n_in,
                              void* d_out, int out_size, void* d_ws, size_t ws_size,
                              hipStream_t stream)
{
  const int*   x    = (const int*)  d_in[0];
  const float* enc  = (const float*)d_in[1];
  const float* h0   = (const float*)d_in[2];
  const float* c0   = (const float*)d_in[3];
  const int*   text = (const int*)  d_in[4];
  const float* emb  = (const float*)d_in[6];
  const float* Vw   = (const float*)d_in[7];
  const float* Vb   = (const float*)d_in[8];
  const float* genw = (const float*)d_in[9];
  const float* genb = (const float*)d_in[10];
  const float* outw = (const float*)d_in[11];
  const float* outb = (const float*)d_in[12];
  const float* Wih  = (const float*)d_in[13];
  const float* Whh  = (const float*)d_in[14];
  const float* bih  = (const float*)d_in[15];
  const float* bhh  = (const float*)d_in[16];
  float* out = (float*)d_out;

  float* ws     = (float*)d_ws;
  float* score  = ws + WS_SCORE;
  float* wbuf   = ws + WS_W;
  float* ctx    = ws + WS_CTX;
  float* hnew   = ws + WS_HNEW;
  float* g0     = ws + WS_G0;
  float* g1     = ws + WS_G1;
  float* g2     = ws + WS_G2;
  float* g3     = ws + WS_G3;
  float* pgen   = ws + WS_PGEN;
  float* part   = ws + WS_PART;
  unsigned short* abf = (unsigned short*)(ws + WS_ABF);
  unsigned short* ad1 = (unsigned short*)(ws + WS_AD1);
  unsigned short* ad2 = (unsigned short*)(ws + WS_AD2);

  k_prep<<<336, 256, 0, stream>>>(x, emb, h0, ad1, ad2);
  k_score<<<6400, 256, 0, stream>>>(enc, h0, Vw, Vb, score);
  k_ctx<<<512, 256, 0, stream>>>(enc, score, wbuf, part);
  k_ctx_reduce<<<64, 256, 0, stream>>>(part, ctx, ad1);
  k_gates<<<256, 128, 0, stream>>>(Wih, Whh, ad1, ad2, g0, g1, g2, g3);
  k_lstm<<<128, 256, 0, stream>>>(c0, bih, bhh, g0, g1, g2, g3, ctx, hnew, abf, out);
  k_pgen<<<64, 256, 0, stream>>>(genw, genb, ctx, hnew, x, emb, pgen);
  k_gemm<<<256, 512, 0, stream>>>(outw, outb, abf, pgen, out);
  k_scatter<<<64, 256, 0, stream>>>(text, wbuf, pgen, out);
}

// Round 13
// 126.143 us; speedup vs baseline: 6.9374x; 1.0249x over previous
//
#include <hip/hip_runtime.h>
#include <hip/hip_bf16.h>

#define BB 64
#define SS 400
#define HH 512
#define EE 300
#define VV 50000
#define KD 812     // E+H (LSTM input width)
#define KG 1324    // 2H+E (gen_in width)
#define KC 1024    // 2H (out_cat width)
#define BV (BB*VV)

typedef __attribute__((ext_vector_type(8))) short bf16x8;
typedef __attribute__((ext_vector_type(4))) float f32x4;
typedef __attribute__((address_space(1))) const void gv_t;
typedef __attribute__((address_space(3))) void lv_t;

// ---- workspace layout (float offsets) ----
#define WS_SCORE 0          // [B*S]
#define WS_W     25600      // [B*S]
#define WS_CTX   51200      // [64][512]
#define WS_HNEW  83968      // [64][512]
#define WS_G0    116736     // [2048][64] f32 gate partials x4
#define WS_G1    247808
#define WS_G2    378880
#define WS_G3    509952
#define WS_PGEN  641024     // [64]
#define WS_PART  641088     // [64][8][512] ctx partials
#define WS_ABF   903232     // ushort [64][1024] bf16 out_cat
#define WS_AD1   936000     // ushort [64][832]  bf16 [xe|ctx|0pad]
#define WS_AD2   962624     // ushort [64][512]  bf16 h_prev

__device__ __forceinline__ float sigm(float x){ return 1.f/(1.f+__expf(-x)); }
__device__ __forceinline__ float ftanh(float x){
  x = fminf(fmaxf(x,-15.f),15.f);
  float e = __expf(2.f*x);
  return (e-1.f)/(e+1.f);
}
__device__ __forceinline__ unsigned short f2bf(float f){
  unsigned int u = __builtin_bit_cast(unsigned int, f);
  u += 0x7fffu + ((u>>16)&1u);
  return (unsigned short)(u>>16);
}

// ---- software-pipelined MFMA segment (compiler-scheduled; used by k_gates) ----
#define LDW(S, off) { w##S##0 = *(const float4*)(wr + (off)*32); \
                      w##S##1 = *(const float4*)(wr + (off)*32 + 4); }
#define LDA(S, off) { a##S##0 = *(const bf16x8*)(a0 + (off)*32); \
                      a##S##1 = *(const bf16x8*)(a1 + (off)*32); \
                      a##S##2 = *(const bf16x8*)(a2 + (off)*32); \
                      a##S##3 = *(const bf16x8*)(a3 + (off)*32); }
#define CONS(S) { union { bf16x8 v; unsigned int u[4]; } bb_; \
  float4 f0_ = w##S##0; float4 f1_ = w##S##1; \
  asm("v_cvt_pk_bf16_f32 %0, %1, %2" : "=v"(bb_.u[0]) : "v"(f0_.x), "v"(f0_.y)); \
  asm("v_cvt_pk_bf16_f32 %0, %1, %2" : "=v"(bb_.u[1]) : "v"(f0_.z), "v"(f0_.w)); \
  asm("v_cvt_pk_bf16_f32 %0, %1, %2" : "=v"(bb_.u[2]) : "v"(f1_.x), "v"(f1_.y)); \
  asm("v_cvt_pk_bf16_f32 %0, %1, %2" : "=v"(bb_.u[3]) : "v"(f1_.z), "v"(f1_.w)); \
  acc0 = __builtin_amdgcn_mfma_f32_16x16x32_bf16(a##S##0, bb_.v, acc0, 0,0,0); \
  acc1 = __builtin_amdgcn_mfma_f32_16x16x32_bf16(a##S##1, bb_.v, acc1, 0,0,0); \
  acc2 = __builtin_amdgcn_mfma_f32_16x16x32_bf16(a##S##2, bb_.v, acc2, 0,0,0); \
  acc3 = __builtin_amdgcn_mfma_f32_16x16x32_bf16(a##S##3, bb_.v, acc3, 0,0,0); }

// depth-2 pipeline, NSTEP % 2 == 0 (k_gates)
template<int NSTEP>
__device__ __forceinline__ void mfma_seg2(const float* __restrict__ wr,
    const unsigned short* __restrict__ a0, const unsigned short* __restrict__ a1,
    const unsigned short* __restrict__ a2, const unsigned short* __restrict__ a3,
    f32x4& acc0, f32x4& acc1, f32x4& acc2, f32x4& acc3)
{
  static_assert(NSTEP % 2 == 0 && NSTEP >= 4, "");
  float4 wA0,wA1, wB0,wB1;
  bf16x8 aA0,aA1,aA2,aA3, aB0,aB1,aB2,aB3;
  LDW(A,0) LDA(A,0)
  LDW(B,1) LDA(B,1)
  #pragma unroll
  for (int ks=0; ks<NSTEP; ks+=2){
    CONS(A) if (ks+2 < NSTEP){ LDW(A,ks+2) LDA(A,ks+2) }
    CONS(B) if (ks+3 < NSTEP){ LDW(B,ks+3) LDA(B,ks+3) }
  }
}

// K0: build bf16 activation buffers: ad1 = [xe(300) | ctx(later) | 0-pad(20)], ad2 = h_prev
__global__ __launch_bounds__(256) void k_prep(const int* __restrict__ x,
    const float* __restrict__ emb, const float* __restrict__ h0,
    unsigned short* __restrict__ ad1, unsigned short* __restrict__ ad2)
{
  int n = blockIdx.x*256 + threadIdx.x;     // 336 blocks: 53248 + 32768
  if (n < BB*832){
    int b = n/832, k = n - b*832;
    if (k < EE) ad1[n] = f2bf(emb[(size_t)x[b]*EE + k]);
    else if (k >= 812) ad1[n] = 0;
  } else {
    int m = n - BB*832;
    ad2[m] = f2bf(h0[m]);
  }
}

// K1: score[b,s] = V_w . tanh(enc[b,s,:] + h_prev[b,:]) + V_b
__global__ __launch_bounds__(256) void k_score(const float* __restrict__ enc,
    const float* __restrict__ h0, const float* __restrict__ Vw,
    const float* __restrict__ Vb, float* __restrict__ score)
{
  int wv = threadIdx.x >> 6, lane = threadIdx.x & 63;
  int pair = blockIdx.x*4 + wv;
  int b = pair / SS;
  int i0 = lane*8;
  const float4* ep = (const float4*)(enc + (size_t)pair*HH + i0);
  const float4* hp = (const float4*)(h0 + b*HH + i0);
  const float4* vp = (const float4*)(Vw + i0);
  float4 e0 = ep[0], e1 = ep[1];
  float4 hv0 = hp[0], hv1 = hp[1];
  float4 v0 = vp[0], v1 = vp[1];
  float sum = ftanh(e0.x+hv0.x)*v0.x + ftanh(e0.y+hv0.y)*v0.y
            + ftanh(e0.z+hv0.z)*v0.z + ftanh(e0.w+hv0.w)*v0.w
            + ftanh(e1.x+hv1.x)*v1.x + ftanh(e1.y+hv1.y)*v1.y
            + ftanh(e1.z+hv1.z)*v1.z + ftanh(e1.w+hv1.w)*v1.w;
  #pragma unroll
  for (int off=32; off; off>>=1) sum += __shfl_xor(sum, off);
  if (lane==0) score[pair] = sum + Vb[0];
}

// K2: per (b, s-chunk): recompute softmax over full row, partial ctx over 50 s.
__global__ __launch_bounds__(256) void k_ctx(const float* __restrict__ enc,
    const float* __restrict__ score, float* __restrict__ wout,
    float* __restrict__ part)
{
  __shared__ float red[256];
  __shared__ float wl[SS];
  int b = blockIdx.x >> 3, sp = blockIdx.x & 7;
  int t = threadIdx.x;
  float v1 = score[b*SS + t];
  float v2 = (t < SS-256) ? score[b*SS + t + 256] : -1e30f;
  red[t] = fmaxf(v1, v2);
  __syncthreads();
  for (int o=128; o; o>>=1){ if (t<o) red[t] = fmaxf(red[t], red[t+o]); __syncthreads(); }
  float mx = red[0];
  __syncthreads();
  float e1 = __expf(v1 - mx);
  float e2 = (t < SS-256) ? __expf(v2 - mx) : 0.f;
  red[t] = e1 + e2;
  __syncthreads();
  for (int o=128; o; o>>=1){ if (t<o) red[t] += red[t+o]; __syncthreads(); }
  float inv = 1.f/red[0];
  float w1 = e1*inv;
  wl[t] = w1;
  if (sp==0) wout[b*SS + t] = w1;
  if (t < SS-256){
    float w2 = e2*inv;
    wl[t+256] = w2;
    if (sp==0) wout[b*SS + t + 256] = w2;
  }
  __syncthreads();
  float a0 = 0.f, a1 = 0.f;
  const float* ebase = enc + ((size_t)b*SS + sp*50)*HH + 2*t;
  #pragma unroll 5
  for (int s=0; s<50; ++s){
    float wg = wl[sp*50 + s];
    float2 e = *(const float2*)(ebase + s*HH);
    a0 += wg * e.x;
    a1 += wg * e.y;
  }
  *(float2*)(part + (size_t)(b*8+sp)*HH + 2*t) = make_float2(a0, a1);
}

// K3: reduce 8 ctx partials -> ctx f32 + ad1 ctx slice (bf16)
__global__ __launch_bounds__(256) void k_ctx_reduce(const float* __restrict__ part,
    float* __restrict__ ctx, unsigned short* __restrict__ ad1)
{
  int b = blockIdx.x, t = threadIdx.x;
  float a0=0.f, a1=0.f;
  #pragma unroll
  for (int sp=0; sp<8; ++sp){
    float2 e = *(const float2*)(part + (size_t)(b*8+sp)*HH + 2*t);
    a0 += e.x; a1 += e.y;
  }
  *(float2*)(ctx + b*HH + 2*t) = make_float2(a0, a1);
  ad1[b*832 + EE + 2*t]     = f2bf(a0);
  ad1[b*832 + EE + 2*t + 1] = f2bf(a1);
}

// K4: gates via MFMA. 512 wave-tiles = 128 j-tiles x 4 K-parts (12/14/8/8 steps).
__global__ __launch_bounds__(128, 4) void k_gates(const float* __restrict__ Wih,
    const float* __restrict__ Whh, const unsigned short* __restrict__ ad1,
    const unsigned short* __restrict__ ad2,
    float* __restrict__ g0, float* __restrict__ g1,
    float* __restrict__ g2, float* __restrict__ g3)
{
  int wt = blockIdx.x*2 + (threadIdx.x >> 6);   // 0..511
  int lane = threadIdx.x & 63;
  int col = lane & 15, kg = lane >> 4;
  int jt = wt >> 2, part = wt & 3;
  int j = jt*16 + col;
  f32x4 acc0={0.f,0.f,0.f,0.f}, acc1=acc0, acc2=acc0, acc3=acc0;
  float* g;
  if (part < 2){
    int k0 = part ? 384 : 0;
    const float* wr = Wih + (size_t)j*KD + k0 + kg*8;
    const unsigned short* a = ad1 + col*832 + k0 + kg*8;
    if (part) mfma_seg2<14>(wr, a, a+16*832, a+32*832, a+48*832, acc0,acc1,acc2,acc3);
    else      mfma_seg2<12>(wr, a, a+16*832, a+32*832, a+48*832, acc0,acc1,acc2,acc3);
    g = part ? g1 : g0;
  } else {
    int k0 = (part==3) ? 256 : 0;
    const float* wr = Whh + (size_t)j*HH + k0 + kg*8;
    const unsigned short* a = ad2 + col*512 + k0 + kg*8;
    mfma_seg2<8>(wr, a, a+16*512, a+32*512, a+48*512, acc0,acc1,acc2,acc3);
    g = (part==3) ? g3 : g2;
  }
  #pragma unroll
  for (int i=0;i<4;i++){
    g[(size_t)j*BB + 0*16 + kg*4 + i] = acc0[i];
    g[(size_t)j*BB + 1*16 + kg*4 + i] = acc1[i];
    g[(size_t)j*BB + 2*16 + kg*4 + i] = acc2[i];
    g[(size_t)j*BB + 3*16 + kg*4 + i] = acc3[i];
  }
}

// K5: LSTM cell elementwise
__global__ __launch_bounds__(256) void k_lstm(const float* __restrict__ c0,
    const float* __restrict__ bih, const float* __restrict__ bhh,
    const float* __restrict__ g0, const float* __restrict__ g1,
    const float* __restrict__ g2, const float* __restrict__ g3,
    const float* __restrict__ ctx, float* __restrict__ hnew,
    unsigned short* __restrict__ abf, float* __restrict__ out)
{
  int n = blockIdx.x*256 + threadIdx.x;   // < 32768
  int b = n & 63, h = n >> 6;
  #define GSUM(off) (g0[(off)*BB+b] + g1[(off)*BB+b] + g2[(off)*BB+b] + g3[(off)*BB+b] + bih[off] + bhh[off])
  float gi = GSUM(h);
  float gf = GSUM(HH+h);
  float gg = GSUM(2*HH+h);
  float go = GSUM(3*HH+h);
  #undef GSUM
  float cn = sigm(gf)*c0[b*HH+h] + sigm(gi)*ftanh(gg);
  float hn = sigm(go)*ftanh(cn);
  out[BV + b*HH + h]          = hn;
  out[BV + BB*HH + b*HH + h]  = cn;
  hnew[b*HH + h] = hn;
  abf[b*KC + h]      = f2bf(hn);
  abf[b*KC + HH + h] = f2bf(ctx[b*HH + h]);
}

// K6: p_gen[b] = sigmoid(gen_w . [ctx, h_new, xe] + gen_b)
__global__ __launch_bounds__(256) void k_pgen(const float* __restrict__ genw,
    const float* __restrict__ genb, const float* __restrict__ ctx,
    const float* __restrict__ hnew, const int* __restrict__ x,
    const float* __restrict__ emb, float* __restrict__ pgen)
{
  __shared__ float red[256];
  int b = blockIdx.x, t = threadIdx.x;
  float p = 0.f;
  for (int k=t; k<KG; k+=256){
    float g = genw[k];
    float v = (k < HH) ? ctx[b*HH + k]
            : (k < 2*HH) ? hnew[b*HH + k - HH]
            : emb[(size_t)x[b]*EE + (k - 2*HH)];
    p += g*v;
  }
  red[t] = p; __syncthreads();
  for (int o=128; o; o>>=1){ if (t<o) red[t] += red[t+o]; __syncthreads(); }
  if (t==0) pgen[b] = sigm(red[0] + genb[0]);
}

// K7 v13: 2 staging streams per CU. 512 blocks (2/CU), 256 thr = 4 waves =
// 4 M-tiles (no K-split across waves -> no comb, no extra barrier). Each
// 16-row tile split into two 32 KB K-half steps, double-buffered DMA; acc
// accumulates across halves in-register; both A-halves preloaded once.
#define ROWB 4096    // bytes per full weight row (1024 f32)
#define HROWB 2048   // bytes per K-half row
#define PADH 2064    // padded LDS half-row stride (2048+16), bank-balanced
__global__ __launch_bounds__(256, 2) void k_gemm(const float* __restrict__ out_w,
    const float* __restrict__ out_b, const unsigned short* __restrict__ abf,
    const float* __restrict__ pgen, float* __restrict__ out)
{
  __shared__ __align__(16) char wlds[2][16*PADH];   // 2 x 33024 B = 66048 B
  int t = threadIdx.x;
  int w = t >> 6, lane = t & 63;        // w = M-tile 0..3
  int col = lane & 15, kg = lane >> 4;
  int bid = blockIdx.x;
  int ts = (bid * 3125) >> 9;           // contiguous tile range (6-7 tiles)
  int te = ((bid + 1) * 3125) >> 9;

  // preload A fragments for BOTH K-halves (tile-invariant)
  const unsigned short* ap = abf + (size_t)(w*16 + col)*KC + kg*8;
  bf16x8 pa0[16], pa1[16];
  #pragma unroll
  for (int ks=0; ks<16; ++ks){
    pa0[ks] = *(const bf16x8*)(ap + ks*32);
    pa1[ks] = *(const bf16x8*)(ap + 512 + ks*32);
  }

  // DMA one 32 KB K-half step: 32 chunks of 1 KB; wave w does chunks w*8..w*8+7
  #define DMASTEP(buf_, tile_, kh_) { \
    const char* wb_ = (const char*)out_w + (size_t)(tile_)*16*ROWB + (kh_)*HROWB; \
    _Pragma("unroll") \
    for (int i_=0;i_<8;i_++){ \
      int c_ = w*8 + i_; \
      int r_ = c_ >> 1, q_ = c_ & 1; \
      __builtin_amdgcn_global_load_lds( \
        (gv_t*)(wb_ + (size_t)r_*ROWB + q_*1024 + lane*16), \
        (lv_t*)(&wlds[buf_][0] + r_*PADH + q_*1024), 16, 0, 0); \
    } }

  #define HALFCOMPUTE(buf_, PA_) { \
    const char* rb_ = &wlds[buf_][0] + col*PADH + kg*32; \
    _Pragma("unroll") \
    for (int ks=0; ks<16; ++ks){ \
      float4 f0 = *(const float4*)(rb_ + ks*128); \
      float4 f1 = *(const float4*)(rb_ + ks*128 + 16); \
      union { bf16x8 v; unsigned int u[4]; } bb; \
      asm("v_cvt_pk_bf16_f32 %0, %1, %2" : "=v"(bb.u[0]) : "v"(f0.x), "v"(f0.y)); \
      asm("v_cvt_pk_bf16_f32 %0, %1, %2" : "=v"(bb.u[1]) : "v"(f0.z), "v"(f0.w)); \
      asm("v_cvt_pk_bf16_f32 %0, %1, %2" : "=v"(bb.u[2]) : "v"(f1.x), "v"(f1.y)); \
      asm("v_cvt_pk_bf16_f32 %0, %1, %2" : "=v"(bb.u[3]) : "v"(f1.z), "v"(f1.w)); \
      acc = __builtin_amdgcn_mfma_f32_16x16x32_bf16(PA_[ks], bb.v, acc, 0,0,0); \
    } }

  DMASTEP(0, ts, 0)
  int cur = 0;
  for (int tile = ts; tile < te; ++tile){
    f32x4 acc = {0.f,0.f,0.f,0.f};

    __syncthreads();                       // buf[cur] (tile,kh=0) ready
    DMASTEP(cur^1, tile, 1)                // (tile,kh=1) in flight
    HALFCOMPUTE(cur, pa0)
    cur ^= 1;

    __syncthreads();                       // buf[cur] (tile,kh=1) ready
    if (tile + 1 < te) DMASTEP(cur^1, tile+1, 0)
    HALFCOMPUTE(cur, pa1)
    cur ^= 1;

    // wave-local epilogue (no cross-wave data -> no barrier)
    int v = tile*16 + col;
    float ob = out_b[v];
    #pragma unroll
    for (int i=0;i<4;i++){
      int b = w*16 + kg*4 + i;
      out[(size_t)b*VV + v] = pgen[b]*(acc[i] + ob);
    }
  }
  #undef DMASTEP
  #undef HALFCOMPUTE
}

// K8: pointer scatter, last-duplicate-wins; text row staged in LDS, branch-free scan.
__global__ __launch_bounds__(256) void k_scatter(const int* __restrict__ text,
    const float* __restrict__ w, const float* __restrict__ pgen,
    float* __restrict__ out)
{
  __shared__ int ts[SS];
  int b = blockIdx.x, t = threadIdx.x;
  ts[t] = text[b*SS + t];
  if (t + 256 < SS) ts[t+256] = text[b*SS + t + 256];
  __syncthreads();
  float pp = 1.f - pgen[b];
  #pragma unroll
  for (int rep=0; rep<2; ++rep){
    int s = t + rep*256;
    if (s < SS){
      int v = ts[s];
      bool dup = false;
      #pragma unroll 4
      for (int s2=s+1; s2<SS; ++s2) dup = dup || (ts[s2]==v);
      if (!dup) out[(size_t)b*VV + v] += pp * w[b*SS + s];
    }
  }
}

extern "C" void kernel_launch(void* const* d_in, const int* in_sizes, int n_in,
                              void* d_out, int out_size, void* d_ws, size_t ws_size,
                              hipStream_t stream)
{
  const int*   x    = (const int*)  d_in[0];
  const float* enc  = (const float*)d_in[1];
  const float* h0   = (const float*)d_in[2];
  const float* c0   = (const float*)d_in[3];
  const int*   text = (const int*)  d_in[4];
  const float* emb  = (const float*)d_in[6];
  const float* Vw   = (const float*)d_in[7];
  const float* Vb   = (const float*)d_in[8];
  const float* genw = (const float*)d_in[9];
  const float* genb = (const float*)d_in[10];
  const float* outw = (const float*)d_in[11];
  const float* outb = (const float*)d_in[12];
  const float* Wih  = (const float*)d_in[13];
  const float* Whh  = (const float*)d_in[14];
  const float* bih  = (const float*)d_in[15];
  const float* bhh  = (const float*)d_in[16];
  float* out = (float*)d_out;

  float* ws     = (float*)d_ws;
  float* score  = ws + WS_SCORE;
  float* wbuf   = ws + WS_W;
  float* ctx    = ws + WS_CTX;
  float* hnew   = ws + WS_HNEW;
  float* g0     = ws + WS_G0;
  float* g1     = ws + WS_G1;
  float* g2     = ws + WS_G2;
  float* g3     = ws + WS_G3;
  float* pgen   = ws + WS_PGEN;
  float* part   = ws + WS_PART;
  unsigned short* abf = (unsigned short*)(ws + WS_ABF);
  unsigned short* ad1 = (unsigned short*)(ws + WS_AD1);
  unsigned short* ad2 = (unsigned short*)(ws + WS_AD2);

  k_prep<<<336, 256, 0, stream>>>(x, emb, h0, ad1, ad2);
  k_score<<<6400, 256, 0, stream>>>(enc, h0, Vw, Vb, score);
  k_ctx<<<512, 256, 0, stream>>>(enc, score, wbuf, part);
  k_ctx_reduce<<<64, 256, 0, stream>>>(part, ctx, ad1);
  k_gates<<<256, 128, 0, stream>>>(Wih, Whh, ad1, ad2, g0, g1, g2, g3);
  k_lstm<<<128, 256, 0, stream>>>(c0, bih, bhh, g0, g1, g2, g3, ctx, hnew, abf, out);
  k_pgen<<<64, 256, 0, stream>>>(genw, genb, ctx, hnew, x, emb, pgen);
  k_gemm<<<512, 256, 0, stream>>>(outw, outb, abf, pgen, out);
  k_scatter<<<64, 256, 0, stream>>>(text, wbuf, pgen, out);
}